// Round 8
// baseline (3600.928 us; speedup 1.0000x reference)
//
#include <hip/hip_runtime.h>
#include <hip/hip_bf16.h>

typedef __bf16 bf16;
typedef __bf16 bf16x8 __attribute__((ext_vector_type(8)));
typedef float f32x4 __attribute__((ext_vector_type(4)));

#define D_MODEL 2048
#define D_INNER 4096
#define ROWS    8192   // B*T

__device__ __forceinline__ void gload_lds16(const void* g, void* l) {
    __builtin_amdgcn_global_load_lds(
        (const __attribute__((address_space(1))) void*)g,
        (__attribute__((address_space(3))) void*)l, 16, 0, 0);
}

// ---------------- fp32 -> bf16 weight convert ----------------
__global__ __launch_bounds__(256) void f2b_kernel(const float* __restrict__ in,
                                                  bf16* __restrict__ out, int n8) {
    int i = blockIdx.x * 256 + threadIdx.x;
    if (i >= n8) return;
    long base = (long)i * 8;
    float4 a = *(const float4*)(in + base);
    float4 b = *(const float4*)(in + base + 4);
    bf16x8 o;
    o[0] = (bf16)a.x; o[1] = (bf16)a.y; o[2] = (bf16)a.z; o[3] = (bf16)a.w;
    o[4] = (bf16)b.x; o[5] = (bf16)b.y; o[6] = (bf16)b.z; o[7] = (bf16)b.w;
    *(bf16x8*)(out + base) = o;
}

// ---------------- rmsnorm (F.normalize * sqrt(D)) fp32 -> bf16 ----------------
__global__ __launch_bounds__(256) void rmsnorm_kernel(const float* __restrict__ x,
                                                      bf16* __restrict__ h) {
    const long row = blockIdx.x;
    const float* xr = x + row * D_MODEL;
    float4 v0 = ((const float4*)xr)[threadIdx.x * 2];
    float4 v1 = ((const float4*)xr)[threadIdx.x * 2 + 1];
    float ss = v0.x*v0.x + v0.y*v0.y + v0.z*v0.z + v0.w*v0.w
             + v1.x*v1.x + v1.y*v1.y + v1.z*v1.z + v1.w*v1.w;
    #pragma unroll
    for (int o = 32; o; o >>= 1) ss += __shfl_xor(ss, o, 64);
    __shared__ float red[4];
    if ((threadIdx.x & 63) == 0) red[threadIdx.x >> 6] = ss;
    __syncthreads();
    float tot = red[0] + red[1] + red[2] + red[3];
    float scale = 45.254834f / fmaxf(sqrtf(tot), 1e-12f);  // sqrt(2048)/max(||x||,eps)
    bf16x8 o;
    o[0] = (bf16)(v0.x*scale); o[1] = (bf16)(v0.y*scale);
    o[2] = (bf16)(v0.z*scale); o[3] = (bf16)(v0.w*scale);
    o[4] = (bf16)(v1.x*scale); o[5] = (bf16)(v1.y*scale);
    o[6] = (bf16)(v1.z*scale); o[7] = (bf16)(v1.w*scale);
    *(bf16x8*)(h + row * D_MODEL + threadIdx.x * 8) = o;
}

// ---------------- depthwise causal conv (4 taps) + SiLU gate ----------------
__global__ __launch_bounds__(256) void conv_gate_kernel(bf16* __restrict__ xz,
                                                        const float* __restrict__ cw,
                                                        const float* __restrict__ cb) {
    const int idx = blockIdx.x * 256 + threadIdx.x;   // ROWS*512 threads
    const int c8  = idx & 511;
    const int row = idx >> 9;
    const int t   = row & 2047;                        // position within batch (T=2048)
    const int c0  = c8 * 8;
    float acc[8];
    float wv[8][4];
    #pragma unroll
    for (int e = 0; e < 8; ++e) {
        float4 f = ((const float4*)cw)[c0 + e];
        wv[e][0] = f.x; wv[e][1] = f.y; wv[e][2] = f.z; wv[e][3] = f.w;
        acc[e] = cb[c0 + e];
    }
    #pragma unroll
    for (int j = 0; j < 4; ++j) {
        if (t + j - 3 >= 0) {
            bf16x8 xv = *(const bf16x8*)(xz + (long)(row + j - 3) * (2*D_INNER) + c0);
            #pragma unroll
            for (int e = 0; e < 8; ++e) acc[e] += (float)xv[e] * wv[e][j];
        }
    }
    bf16* zp = xz + (long)row * (2*D_INNER) + D_INNER + c0;
    bf16x8 zv = *(const bf16x8*)zp;
    bf16x8 yv;
    #pragma unroll
    for (int e = 0; e < 8; ++e) {
        float xc = acc[e];
        float s1 = xc / (1.f + __expf(-xc));
        float z  = (float)zv[e];
        float s2 = z / (1.f + __expf(-z));
        yv[e] = (bf16)(s1 * s2);
    }
    *(bf16x8*)zp = yv;
}

// ---------------- bf16 GEMM v8 (fully pipelined frag reads) ----------------
// 256x256 tile, BK=64, 512 threads = 8 waves (2M x 4N), per-wave 128x64.
// v7's LDS layout/swizzle/staging/epilogue kept. NEW: every ds_read block is
// issued one MFMA-cluster AHEAD into role-rotating register sets (FA0/FA1
// for A; two B sets alternating per K-tile), so no wave ever sits in a
// serial read gap between quadrants.
//   P_A(t): lgkm(0)[drain BH] | issue A1(t)->FA1 | stgB(t+2) |
//           q2=FA0xBH[cs] | lgkm(0) | q3=FA1xBH[cs] | vmcnt(4) | bar
//   P_B(t): issue A0,BL,BH(t+1) from other dbuf (FA0 first, BH last) |
//           stgA(t+2) | q4=FA1xBL[cs] | lgkm(4) (BH lands under q1) |
//           q1(t+1)=FA0xBL[ns] | bar          (reads+q1 skipped on last tile)
// Race ledger identical to v5/v7: vmcnt(4) after stgB(t+2) retires stgA(t+1)
// (FIFO) -> tile t+1 fully in LDS before any post-barrier read; every staged
// region's readers are lgkm'd >=1 barrier before the stage issues; vmcnt
// never drains in-loop; vmcnt(0) before the epilogue LDS reuse.
// EPI: 0 = store bf16, 1 = relu+store bf16, 2 = fp32 res-add + store fp32
template<int EPI>
__global__ __launch_bounds__(512, 2) void gemm_bt(
        const bf16* __restrict__ A, long lda,
        const bf16* __restrict__ B,
        void* __restrict__ C, const float* __restrict__ res,
        int N, int K, int gx) {
    __shared__ __align__(16) char LB[131072];
    const int tid = threadIdx.x;
    const int w   = tid >> 6;
    const int l   = tid & 63;
    const int lr  = l & 15;

    // bijective XCD swizzle (all grids %8 == 0)
    const int nwg = gridDim.x;
    const int qq  = nwg >> 3;
    const int sw  = (blockIdx.x & 7) * qq + (blockIdx.x >> 3);
    const int bx  = sw % gx, by = sw / gx;
    const long rowBase = (long)by * 256;
    const long colBase = (long)bx * 256;

    // staging sources: thread covers row (w*8 + l>>3), 16B chunk (l&7)^((l>>3)&7)
    const int srow = w * 8 + (l >> 3);
    const int schk = (l & 7) ^ ((l >> 3) & 7);
    const bf16* aSrc = A + (rowBase + srow) * lda + schk * 8;
    const bf16* bSrc = B + (colBase + srow) * (long)K + schk * 8;
    const long lda64 = 64 * lda;
    const long ldb64 = 64 * (long)K;
    const int  w1024 = w * 1024;

    auto stgA = [&](int DBB, int kt) {   // A halves -> dbuf DBB (4 loads)
        const bf16* s = aSrc + (long)kt * 64;
        gload_lds16(s,            LB + DBB +     0 + w1024);
        gload_lds16(s +   lda64,  LB + DBB +  8192 + w1024);
        gload_lds16(s + 2*lda64,  LB + DBB + 16384 + w1024);
        gload_lds16(s + 3*lda64,  LB + DBB + 24576 + w1024);
    };
    auto stgB = [&](int DBB, int kt) {   // B halves -> dbuf DBB (4 loads)
        const bf16* s = bSrc + (long)kt * 64;
        gload_lds16(s,            LB + DBB + 32768 + w1024);
        gload_lds16(s +   ldb64,  LB + DBB + 40960 + w1024);
        gload_lds16(s + 2*ldb64,  LB + DBB + 49152 + w1024);
        gload_lds16(s + 3*ldb64,  LB + DBB + 57344 + w1024);
    };

    // fragment read offsets (swizzled); row&7 == l&7 for all frag rows
    const int cx0 = (((l >> 4)    ) ^ (l & 7)) << 4;
    const int cx1 = (((l >> 4) + 4) ^ (l & 7)) << 4;
    const int hm = w >> 2;     // A half (M)
    const int q  = w & 3;      // B quarter (N)
    int aRow[8], bRow[4];
    #pragma unroll
    for (int m = 0; m < 8; ++m) aRow[m] = hm * 16384 + (m * 16 + lr) * 128;
    #pragma unroll
    for (int n = 0; n < 4; ++n)
        bRow[n] = 32768 + (q >> 1) * 16384 + ((q & 1) * 64 + n * 16 + lr) * 128;

    const int nt  = K >> 6;
    const int nit = nt >> 1;
    f32x4 acc[8][4] = {};
    bf16x8 FA0[4][2], FA1[4][2], BLs[2][2][2], BHs[2][2][2];

    // prologue: stage tile0 -> dbuf0, tile1 -> dbuf1 (B then A per tile)
    stgB(0, 0);      stgA(0, 0);
    stgB(65536, 1);  stgA(65536, 1);
    asm volatile("s_waitcnt vmcnt(8)" ::: "memory");   // tile 0 landed
    __builtin_amdgcn_s_barrier();
    __builtin_amdgcn_sched_barrier(0);
    // read tile0: FA0=A0, BLs[0]=B0, BHs[0]=B1 (BH last)
    #pragma unroll
    for (int m = 0; m < 4; ++m) {
        FA0[m][0] = *(const bf16x8*)(LB + aRow[m] + cx0);
        FA0[m][1] = *(const bf16x8*)(LB + aRow[m] + cx1);
    }
    #pragma unroll
    for (int n = 0; n < 2; ++n) {
        BLs[0][n][0] = *(const bf16x8*)(LB + bRow[n]     + cx0);
        BLs[0][n][1] = *(const bf16x8*)(LB + bRow[n]     + cx1);
    }
    #pragma unroll
    for (int n = 0; n < 2; ++n) {
        BHs[0][n][0] = *(const bf16x8*)(LB + bRow[n + 2] + cx0);
        BHs[0][n][1] = *(const bf16x8*)(LB + bRow[n + 2] + cx1);
    }
    asm volatile("s_waitcnt lgkmcnt(4)" ::: "memory");   // FA0+BL landed
    __builtin_amdgcn_sched_barrier(0);
    __builtin_amdgcn_s_setprio(1);
    #pragma unroll
    for (int m = 0; m < 4; ++m)
        #pragma unroll
        for (int n = 0; n < 2; ++n) {
            acc[m][n] = __builtin_amdgcn_mfma_f32_16x16x32_bf16(FA0[m][0], BLs[0][n][0], acc[m][n], 0, 0, 0);
            acc[m][n] = __builtin_amdgcn_mfma_f32_16x16x32_bf16(FA0[m][1], BLs[0][n][1], acc[m][n], 0, 0, 0);
        }
    __builtin_amdgcn_s_setprio(0);
    __builtin_amdgcn_s_barrier();

    for (int it = 0; it < nit; ++it) {
        int kA = 2 * it + 2; if (kA >= nt) kA = 0;     // dummy clamp in tail
        int kB = 2 * it + 3; if (kB >= nt) kB = 0;
        #pragma unroll
        for (int db = 0; db < 2; ++db) {
            const int cs = db;         // current B set
            const int ns = db ^ 1;     // next B set
            const int DBB = db * 65536;
            const char* Lb = LB + DBB;
            const char* Ln = LB + (DBB ^ 65536);
            const int kst = db ? kB : kA;
            const bool full = (db == 0) || (it < nit - 1);

            // ================= P_A =================
            asm volatile("s_waitcnt lgkmcnt(0)" ::: "memory");  // drain BH[cs]
            __builtin_amdgcn_sched_barrier(0);
            #pragma unroll
            for (int m = 0; m < 4; ++m) {                       // issue A1(t)->FA1
                FA1[m][0] = *(const bf16x8*)(Lb + aRow[m + 4] + cx0);
                FA1[m][1] = *(const bf16x8*)(Lb + aRow[m + 4] + cx1);
            }
            __builtin_amdgcn_sched_barrier(0);
            stgB(DBB, kst);
            __builtin_amdgcn_s_setprio(1);
            #pragma unroll
            for (int m = 0; m < 4; ++m)                         // q2: FA0 x BH[cs]
                #pragma unroll
                for (int n = 0; n < 2; ++n) {
                    acc[m][n + 2] = __builtin_amdgcn_mfma_f32_16x16x32_bf16(FA0[m][0], BHs[cs][n][0], acc[m][n + 2], 0, 0, 0);
                    acc[m][n + 2] = __builtin_amdgcn_mfma_f32_16x16x32_bf16(FA0[m][1], BHs[cs][n][1], acc[m][n + 2], 0, 0, 0);
                }
            __builtin_amdgcn_s_setprio(0);
            asm volatile("s_waitcnt lgkmcnt(0)" ::: "memory");  // FA1 landed
            __builtin_amdgcn_sched_barrier(0);
            __builtin_amdgcn_s_setprio(1);
            #pragma unroll
            for (int m = 0; m < 4; ++m)                         // q3: FA1 x BH[cs]
                #pragma unroll
                for (int n = 0; n < 2; ++n) {
                    acc[m + 4][n + 2] = __builtin_amdgcn_mfma_f32_16x16x32_bf16(FA1[m][0], BHs[cs][n][0], acc[m + 4][n + 2], 0, 0, 0);
                    acc[m + 4][n + 2] = __builtin_amdgcn_mfma_f32_16x16x32_bf16(FA1[m][1], BHs[cs][n][1], acc[m + 4][n + 2], 0, 0, 0);
                }
            __builtin_amdgcn_s_setprio(0);
            asm volatile("s_waitcnt vmcnt(4)" ::: "memory");    // t+1 fully landed
            __builtin_amdgcn_s_barrier();
            __builtin_amdgcn_sched_barrier(0);

            // ================= P_B =================
            if (full) {
                // issue t+1 reads from other dbuf: FA0 first, BL, BH last
                #pragma unroll
                for (int m = 0; m < 4; ++m) {
                    FA0[m][0] = *(const bf16x8*)(Ln + aRow[m] + cx0);
                    FA0[m][1] = *(const bf16x8*)(Ln + aRow[m] + cx1);
                }
                #pragma unroll
                for (int n = 0; n < 2; ++n) {
                    BLs[ns][n][0] = *(const bf16x8*)(Ln + bRow[n]     + cx0);
                    BLs[ns][n][1] = *(const bf16x8*)(Ln + bRow[n]     + cx1);
                }
                #pragma unroll
                for (int n = 0; n < 2; ++n) {
                    BHs[ns][n][0] = *(const bf16x8*)(Ln + bRow[n + 2] + cx0);
                    BHs[ns][n][1] = *(const bf16x8*)(Ln + bRow[n + 2] + cx1);
                }
                __builtin_amdgcn_sched_barrier(0);
            }
            stgA(DBB, kst);
            __builtin_amdgcn_s_setprio(1);
            #pragma unroll
            for (int m = 0; m < 4; ++m)                         // q4: FA1 x BL[cs]
                #pragma unroll
                for (int n = 0; n < 2; ++n) {
                    acc[m + 4][n] = __builtin_amdgcn_mfma_f32_16x16x32_bf16(FA1[m][0], BLs[cs][n][0], acc[m + 4][n], 0, 0, 0);
                    acc[m + 4][n] = __builtin_amdgcn_mfma_f32_16x16x32_bf16(FA1[m][1], BLs[cs][n][1], acc[m + 4][n], 0, 0, 0);
                }
            __builtin_amdgcn_s_setprio(0);
            if (full) {
                asm volatile("s_waitcnt lgkmcnt(4)" ::: "memory");  // FA0+BL landed; BH under q1
                __builtin_amdgcn_sched_barrier(0);
                __builtin_amdgcn_s_setprio(1);
                #pragma unroll
                for (int m = 0; m < 4; ++m)                     // q1(t+1): FA0 x BL[ns]
                    #pragma unroll
                    for (int n = 0; n < 2; ++n) {
                        acc[m][n] = __builtin_amdgcn_mfma_f32_16x16x32_bf16(FA0[m][0], BLs[ns][n][0], acc[m][n], 0, 0, 0);
                        acc[m][n] = __builtin_amdgcn_mfma_f32_16x16x32_bf16(FA0[m][1], BLs[ns][n][1], acc[m][n], 0, 0, 0);
                    }
                __builtin_amdgcn_s_setprio(0);
            }
            __builtin_amdgcn_s_barrier();
            __builtin_amdgcn_sched_barrier(0);
        }
    }

    // drain all DMAs (incl. dummy tail prefetches), then barrier: after this
    // no wave has LDS writes in flight -> safe to reuse LB for the epilogue.
    asm volatile("s_waitcnt vmcnt(0)" ::: "memory");
    __builtin_amdgcn_s_barrier();

    // epilogue: C/D layout col = lane&15, row = (lane>>4)*4 + reg.
    // Per-wave private 16KB LDS region, chunk-XOR swizzle (2-way free).
    const int lg = l >> 4;
    const long wrow = rowBase + hm * 128;
    const long wcol = colBase + q * 64;
    char* ep = LB + w * 16384;

    if (EPI == 2) {
        // two passes of 64 rows: [64][64 f32], row stride 256B, 16 chunks
        #pragma unroll
        for (int mh = 0; mh < 2; ++mh) {
            #pragma unroll
            for (int m = 0; m < 4; ++m) {
                #pragma unroll
                for (int n = 0; n < 4; ++n) {
                    f32x4 v = acc[mh * 4 + m][n];
                    #pragma unroll
                    for (int r = 0; r < 4; ++r) {
                        int rowr = m * 16 + lg * 4 + r;
                        int chnk = (n * 4 + (lr >> 2)) ^ (rowr & 7);
                        *(float*)(ep + rowr * 256 + chnk * 16 + (lr & 3) * 4) = v[r];
                    }
                }
            }
            asm volatile("s_waitcnt lgkmcnt(0)" ::: "memory");
            #pragma unroll
            for (int i = 0; i < 16; ++i) {
                int rr = i * 4 + (l >> 4);
                float4 lv = *(float4*)(ep + rr * 256 + (((l & 15) ^ (rr & 7)) * 16));
                long off = (wrow + mh * 64 + rr) * N + wcol + (l & 15) * 4;
                float4 rv = *(const float4*)(res + off);
                lv.x += rv.x; lv.y += rv.y; lv.z += rv.z; lv.w += rv.w;
                *(float4*)((float*)C + off) = lv;
            }
            if (mh == 0) { asm volatile("s_waitcnt lgkmcnt(0) vmcnt(0)" ::: "memory"); }
        }
    } else {
        // [128][64 bf16], row stride 128B, 8 chunks
        #pragma unroll
        for (int m = 0; m < 8; ++m) {
            #pragma unroll
            for (int n = 0; n < 4; ++n) {
                f32x4 v = acc[m][n];
                #pragma unroll
                for (int r = 0; r < 4; ++r) {
                    int rowr = m * 16 + lg * 4 + r;
                    int chnk = (n * 2 + (lr >> 3)) ^ (rowr & 7);
                    float val = (EPI == 1) ? fmaxf(v[r], 0.f) : v[r];
                    *(bf16*)(ep + rowr * 128 + chnk * 16 + (lr & 7) * 2) = (bf16)val;
                }
            }
        }
        asm volatile("s_waitcnt lgkmcnt(0)" ::: "memory");
        #pragma unroll
        for (int i = 0; i < 16; ++i) {
            int rr = i * 8 + (l >> 3);
            uint4 lv = *(uint4*)(ep + rr * 128 + (((l & 7) ^ (rr & 7)) * 16));
            *(uint4*)((bf16*)C + (wrow + rr) * N + wcol + (l & 7) * 8) = lv;
        }
    }
}

extern "C" void kernel_launch(void* const* d_in, const int* in_sizes, int n_in,
                              void* d_out, int out_size, void* d_ws, size_t ws_size,
                              hipStream_t stream) {
    const float* x      = (const float*)d_in[0];
    const float* W_in   = (const float*)d_in[1];
    const float* cw     = (const float*)d_in[2];
    const float* cb     = (const float*)d_in[3];
    const float* W_out  = (const float*)d_in[4];
    const float* W_mlp1 = (const float*)d_in[5];
    const float* W_mlp2 = (const float*)d_in[6];
    float* out = (float*)d_out;

    char* ws  = (char*)d_ws;
    bf16* wW  = (bf16*)(ws);                    // 33.55 MB (max bf16 weight)
    bf16* h   = (bf16*)(ws + 33554432);         // 33.55 MB (h / h2)
    bf16* xz  = (bf16*)(ws + 67108864);         // 134.2 MB (xz / m1)
    float* x2 = (float*)(ws + 201326592);       // 67.1 MB
    bf16* y   = xz + D_INNER;                   // in-place over z half, lda = 8192
    bf16* m1  = xz;

    dim3 blk(256);
    dim3 gblk(512);

    // mamba branch
    f2b_kernel<<<dim3(8192), blk, 0, stream>>>(W_in, wW, 16777216/8);
    rmsnorm_kernel<<<dim3(ROWS), blk, 0, stream>>>(x, h);
    gemm_bt<0><<<dim3(1024), gblk, 0, stream>>>(h, D_MODEL, wW, xz, nullptr, 2*D_INNER, D_MODEL, 32);
    conv_gate_kernel<<<dim3(16384), blk, 0, stream>>>(xz, cw, cb);
    f2b_kernel<<<dim3(4096), blk, 0, stream>>>(W_out, wW, 8388608/8);
    gemm_bt<2><<<dim3(256), gblk, 0, stream>>>(y, 2*D_INNER, wW, x2, x, D_MODEL, D_INNER, 8);

    // mlp branch
    rmsnorm_kernel<<<dim3(ROWS), blk, 0, stream>>>(x2, h);
    f2b_kernel<<<dim3(8192), blk, 0, stream>>>(W_mlp1, wW, 16777216/8);
    gemm_bt<1><<<dim3(1024), gblk, 0, stream>>>(h, D_MODEL, wW, m1, nullptr, 4*D_MODEL, D_MODEL, 32);
    f2b_kernel<<<dim3(8192), blk, 0, stream>>>(W_mlp2, wW, 16777216/8);
    gemm_bt<2><<<dim3(256), gblk, 0, stream>>>(m1, 4*D_MODEL, wW, out, x2, D_MODEL, 4*D_MODEL, 8);
}

// Round 10
// 1160.153 us; speedup vs baseline: 3.1038x; 3.1038x over previous
//
#include <hip/hip_runtime.h>
#include <hip/hip_bf16.h>

typedef __bf16 bf16;
typedef __bf16 bf16x8 __attribute__((ext_vector_type(8)));
typedef float f32x4 __attribute__((ext_vector_type(4)));

#define D_MODEL 2048
#define D_INNER 4096
#define ROWS    8192   // B*T

__device__ __forceinline__ void gload_lds16(const void* g, void* l) {
    __builtin_amdgcn_global_load_lds(
        (const __attribute__((address_space(1))) void*)g,
        (__attribute__((address_space(3))) void*)l, 16, 0, 0);
}

// ---------------- fp32 -> bf16 weight convert ----------------
__global__ __launch_bounds__(256) void f2b_kernel(const float* __restrict__ in,
                                                  bf16* __restrict__ out, int n8) {
    int i = blockIdx.x * 256 + threadIdx.x;
    if (i >= n8) return;
    long base = (long)i * 8;
    float4 a = *(const float4*)(in + base);
    float4 b = *(const float4*)(in + base + 4);
    bf16x8 o;
    o[0] = (bf16)a.x; o[1] = (bf16)a.y; o[2] = (bf16)a.z; o[3] = (bf16)a.w;
    o[4] = (bf16)b.x; o[5] = (bf16)b.y; o[6] = (bf16)b.z; o[7] = (bf16)b.w;
    *(bf16x8*)(out + base) = o;
}

// ---------------- rmsnorm (F.normalize * sqrt(D)) fp32 -> bf16 ----------------
__global__ __launch_bounds__(256) void rmsnorm_kernel(const float* __restrict__ x,
                                                      bf16* __restrict__ h) {
    const long row = blockIdx.x;
    const float* xr = x + row * D_MODEL;
    float4 v0 = ((const float4*)xr)[threadIdx.x * 2];
    float4 v1 = ((const float4*)xr)[threadIdx.x * 2 + 1];
    float ss = v0.x*v0.x + v0.y*v0.y + v0.z*v0.z + v0.w*v0.w
             + v1.x*v1.x + v1.y*v1.y + v1.z*v1.z + v1.w*v1.w;
    #pragma unroll
    for (int o = 32; o; o >>= 1) ss += __shfl_xor(ss, o, 64);
    __shared__ float red[4];
    if ((threadIdx.x & 63) == 0) red[threadIdx.x >> 6] = ss;
    __syncthreads();
    float tot = red[0] + red[1] + red[2] + red[3];
    float scale = 45.254834f / fmaxf(sqrtf(tot), 1e-12f);  // sqrt(2048)/max(||x||,eps)
    bf16x8 o;
    o[0] = (bf16)(v0.x*scale); o[1] = (bf16)(v0.y*scale);
    o[2] = (bf16)(v0.z*scale); o[3] = (bf16)(v0.w*scale);
    o[4] = (bf16)(v1.x*scale); o[5] = (bf16)(v1.y*scale);
    o[6] = (bf16)(v1.z*scale); o[7] = (bf16)(v1.w*scale);
    *(bf16x8*)(h + row * D_MODEL + threadIdx.x * 8) = o;
}

// ---------------- depthwise causal conv (4 taps) + SiLU gate ----------------
__global__ __launch_bounds__(256) void conv_gate_kernel(bf16* __restrict__ xz,
                                                        const float* __restrict__ cw,
                                                        const float* __restrict__ cb) {
    const int idx = blockIdx.x * 256 + threadIdx.x;   // ROWS*512 threads
    const int c8  = idx & 511;
    const int row = idx >> 9;
    const int t   = row & 2047;                        // position within batch (T=2048)
    const int c0  = c8 * 8;
    float acc[8];
    float wv[8][4];
    #pragma unroll
    for (int e = 0; e < 8; ++e) {
        float4 f = ((const float4*)cw)[c0 + e];
        wv[e][0] = f.x; wv[e][1] = f.y; wv[e][2] = f.z; wv[e][3] = f.w;
        acc[e] = cb[c0 + e];
    }
    #pragma unroll
    for (int j = 0; j < 4; ++j) {
        if (t + j - 3 >= 0) {
            bf16x8 xv = *(const bf16x8*)(xz + (long)(row + j - 3) * (2*D_INNER) + c0);
            #pragma unroll
            for (int e = 0; e < 8; ++e) acc[e] += (float)xv[e] * wv[e][j];
        }
    }
    bf16* zp = xz + (long)row * (2*D_INNER) + D_INNER + c0;
    bf16x8 zv = *(const bf16x8*)zp;
    bf16x8 yv;
    #pragma unroll
    for (int e = 0; e < 8; ++e) {
        float xc = acc[e];
        float s1 = xc / (1.f + __expf(-xc));
        float z  = (float)zv[e];
        float s2 = z / (1.f + __expf(-z));
        yv[e] = (bf16)(s1 * s2);
    }
    *(bf16x8*)zp = yv;
}

// ---------------- bf16 GEMM v9 "w4": 4 waves, per-wave 128x128 ----------------
// At 8 waves x (128x64)/wave the LDS pipe (192 b128/CU/K-tile x ~12cyc =
// 2304cyc) co-saturates with MFMA (2484cyc) -> ~51% cap. 4 waves x
// (128x128)/wave: 128 reads/CU/K-tile = 1536cyc << MFMA. acc=256 regs ->
// 1 wave/SIMD, __launch_bounds__(256,1).
// lgkmcnt is 4-bit (max 15): k1 issue is split a1(8) | lgkmcnt(8) [FIFO:
// retires k0's 16] | b1(8) | MFMA k0 | lgkmcnt(0) | stage | MFMA k1.
// vmcnt(16)/tile retires exactly tile t+1; k0(t+1) pre-read after barrier.
// EPI: 0 = store bf16, 1 = relu+store bf16
template<int EPI>
__global__ __launch_bounds__(256, 1) void gemm_w4(
        const bf16* __restrict__ A, long lda,
        const bf16* __restrict__ B,
        bf16* __restrict__ C,
        int N, int K, int gx) {
    __shared__ __align__(16) char LB[131072];
    const int tid = threadIdx.x;
    const int w   = tid >> 6;
    const int l   = tid & 63;
    const int lr  = l & 15;

    // bijective XCD swizzle (grids %8 == 0)
    const int nwg = gridDim.x;
    const int qq  = nwg >> 3;
    const int sw  = (blockIdx.x & 7) * qq + (blockIdx.x >> 3);
    const int bx  = sw % gx, by = sw / gx;
    const long rowBase = (long)by * 256;
    const long colBase = (long)bx * 256;

    // staging: thread covers row tid>>3 (0..31) per 32-row slab, 16B chunk
    // (tid&7)^((tid>>3)&7) (inverse swizzle on the global source)
    const int srow = tid >> 3;
    const int schk = (tid & 7) ^ ((tid >> 3) & 7);
    const bf16* aSrc = A + (rowBase + srow) * lda + schk * 8;
    const bf16* bSrc = B + (colBase + srow) * (long)K + schk * 8;
    const int w1024 = w * 1024;

    auto stg = [&](int DBB, int kt) {   // full tile: 8 A-slabs + 8 B-slabs
        const bf16* sa = aSrc + (long)kt * 64;
        const bf16* sb = bSrc + (long)kt * 64;
        #pragma unroll
        for (int i = 0; i < 8; ++i)
            gload_lds16(sa + (long)(32 * i) * lda, LB + DBB + i * 4096 + w1024);
        #pragma unroll
        for (int i = 0; i < 8; ++i)
            gload_lds16(sb + (long)(32 * i) * (long)K, LB + DBB + 32768 + i * 4096 + w1024);
    };

    // fragment offsets (swizzled); frag row & 7 == l & 7
    const int wr = (w >> 1) * 128;
    const int wc = (w & 1) * 128;
    const int cx0 = (((l >> 4)    ) ^ (l & 7)) << 4;
    const int cx1 = (((l >> 4) + 4) ^ (l & 7)) << 4;
    int aRow[8], bRow[8];
    #pragma unroll
    for (int m = 0; m < 8; ++m) aRow[m] = (wr + m * 16 + lr) * 128;
    #pragma unroll
    for (int n = 0; n < 8; ++n) bRow[n] = 32768 + (wc + n * 16 + lr) * 128;

    const int nt = K >> 6;
    f32x4 acc[8][8] = {};
    bf16x8 a0[8], b0[8], a1[8], b1[8];

    // prologue: tile0 -> buf0, tile1 -> buf1 (32 loads); wait tile0; read k0
    stg(0, 0);
    stg(65536, 1);
    asm volatile("s_waitcnt vmcnt(16)" ::: "memory");
    __builtin_amdgcn_s_barrier();
    __builtin_amdgcn_sched_barrier(0);
    #pragma unroll
    for (int m = 0; m < 8; ++m) a0[m] = *(const bf16x8*)(LB + aRow[m] + cx0);
    #pragma unroll
    for (int n = 0; n < 8; ++n) b0[n] = *(const bf16x8*)(LB + bRow[n] + cx0);

    for (int t = 0; t < nt; ++t) {
        const char* Lb = (const char*)LB + ((t & 1) << 16);
        int kst = t + 2; if (kst >= nt) kst = 0;   // dummy clamp in tail

        // 1a. issue k1(t) A reads (8) -> 24 outstanding
        #pragma unroll
        for (int m = 0; m < 8; ++m) a1[m] = *(const bf16x8*)(Lb + aRow[m] + cx1);
        // 2. k0 frags ready: FIFO retires k0's 16, a1's 8 remain
        asm volatile("s_waitcnt lgkmcnt(8)" ::: "memory");
        __builtin_amdgcn_sched_barrier(0);
        // 1b. issue k1(t) B reads (8) -- land under k0's MFMAs
        #pragma unroll
        for (int n = 0; n < 8; ++n) b1[n] = *(const bf16x8*)(Lb + bRow[n] + cx1);
        __builtin_amdgcn_sched_barrier(0);
        // 3. MFMA k0 (64)
        __builtin_amdgcn_s_setprio(1);
        #pragma unroll
        for (int m = 0; m < 8; ++m)
            #pragma unroll
            for (int n = 0; n < 8; ++n)
                acc[m][n] = __builtin_amdgcn_mfma_f32_16x16x32_bf16(a0[m], b0[n], acc[m][n], 0, 0, 0);
        __builtin_amdgcn_s_setprio(0);
        // 4. k1 frags ready
        asm volatile("s_waitcnt lgkmcnt(0)" ::: "memory");
        __builtin_amdgcn_sched_barrier(0);
        // 5. write-behind stage of tile t+2 into current buf (data is in regs)
        stg((t & 1) << 16, kst);
        // 6. MFMA k1 (64)
        __builtin_amdgcn_s_setprio(1);
        #pragma unroll
        for (int m = 0; m < 8; ++m)
            #pragma unroll
            for (int n = 0; n < 8; ++n)
                acc[m][n] = __builtin_amdgcn_mfma_f32_16x16x32_bf16(a1[m], b1[n], acc[m][n], 0, 0, 0);
        __builtin_amdgcn_s_setprio(0);
        // 7. retire tile t+1's 16 loads (t+2's 16 stay in flight); 8. barrier
        asm volatile("s_waitcnt vmcnt(16)" ::: "memory");
        __builtin_amdgcn_s_barrier();
        __builtin_amdgcn_sched_barrier(0);
        // 9. pre-read k0(t+1) from the other buf
        if (t + 1 < nt) {
            const char* Ln = (const char*)LB + (((t + 1) & 1) << 16);
            #pragma unroll
            for (int m = 0; m < 8; ++m) a0[m] = *(const bf16x8*)(Ln + aRow[m] + cx0);
            #pragma unroll
            for (int n = 0; n < 8; ++n) b0[n] = *(const bf16x8*)(Ln + bRow[n] + cx0);
        }
    }

    // drain dummy prefetch DMAs; then LDS is safe to reuse
    asm volatile("s_waitcnt vmcnt(0)" ::: "memory");
    __builtin_amdgcn_s_barrier();

    // epilogue: C/D col = lane&15, row = (lane>>4)*4 + reg.
    // Per-wave private 32KB LDS region [128 rows][128 bf16], chunk-XOR swizzle.
    const int lg = l >> 4;
    char* ep = LB + w * 32768;
    #pragma unroll
    for (int m = 0; m < 8; ++m) {
        #pragma unroll
        for (int n = 0; n < 8; ++n) {
            f32x4 v = acc[m][n];
            #pragma unroll
            for (int r = 0; r < 4; ++r) {
                int rowr = m * 16 + lg * 4 + r;
                int chnk = (n * 2 + (lr >> 3)) ^ (rowr & 7);
                float val = (EPI == 1) ? fmaxf(v[r], 0.f) : v[r];
                *(bf16*)(ep + rowr * 256 + chnk * 16 + (lr & 7) * 2) = (bf16)val;
            }
        }
    }
    asm volatile("s_waitcnt lgkmcnt(0)" ::: "memory");
    #pragma unroll
    for (int i = 0; i < 32; ++i) {
        int rr = i * 4 + (l >> 4);
        int lc = l & 15;
        uint4 lv = *(uint4*)(ep + rr * 256 + ((lc ^ (rr & 7)) * 16));
        *(uint4*)(C + (rowBase + wr + rr) * N + colBase + wc + lc * 8) = lv;
    }
}

// ---------------- bf16 GEMM v7 (proven; used for EPI=2): C = A @ B^T -------
// 256x256 tile, BK=64, 512 threads = 8 waves (2M x 4N), per-wave 128x64.
template<int EPI>
__global__ __launch_bounds__(512, 2) void gemm_bt(
        const bf16* __restrict__ A, long lda,
        const bf16* __restrict__ B,
        void* __restrict__ C, const float* __restrict__ res,
        int N, int K, int gx) {
    __shared__ __align__(16) char LB[131072];
    const int tid = threadIdx.x;
    const int w   = tid >> 6;
    const int l   = tid & 63;
    const int lr  = l & 15;

    const int nwg = gridDim.x;
    const int qq  = nwg >> 3;
    const int sw  = (blockIdx.x & 7) * qq + (blockIdx.x >> 3);
    const int bx  = sw % gx, by = sw / gx;
    const long rowBase = (long)by * 256;
    const long colBase = (long)bx * 256;

    const int srow = w * 8 + (l >> 3);
    const int schk = (l & 7) ^ ((l >> 3) & 7);
    const bf16* aSrc = A + (rowBase + srow) * lda + schk * 8;
    const bf16* bSrc = B + (colBase + srow) * (long)K + schk * 8;
    const long lda64 = 64 * lda;
    const long ldb64 = 64 * (long)K;
    const int  w1024 = w * 1024;

    auto stgA = [&](int DBB, int kt) {
        const bf16* s = aSrc + (long)kt * 64;
        gload_lds16(s,            LB + DBB +     0 + w1024);
        gload_lds16(s +   lda64,  LB + DBB +  8192 + w1024);
        gload_lds16(s + 2*lda64,  LB + DBB + 16384 + w1024);
        gload_lds16(s + 3*lda64,  LB + DBB + 24576 + w1024);
    };
    auto stgB = [&](int DBB, int kt) {
        const bf16* s = bSrc + (long)kt * 64;
        gload_lds16(s,            LB + DBB + 32768 + w1024);
        gload_lds16(s +   ldb64,  LB + DBB + 40960 + w1024);
        gload_lds16(s + 2*ldb64,  LB + DBB + 49152 + w1024);
        gload_lds16(s + 3*ldb64,  LB + DBB + 57344 + w1024);
    };

    const int cx0 = (((l >> 4)    ) ^ (l & 7)) << 4;
    const int cx1 = (((l >> 4) + 4) ^ (l & 7)) << 4;
    const int hm = w >> 2;
    const int q  = w & 3;
    int aRow[8], bRow[4];
    #pragma unroll
    for (int m = 0; m < 8; ++m) aRow[m] = hm * 16384 + (m * 16 + lr) * 128;
    #pragma unroll
    for (int n = 0; n < 4; ++n)
        bRow[n] = 32768 + (q >> 1) * 16384 + ((q & 1) * 64 + n * 16 + lr) * 128;

    const int nt  = K >> 6;
    const int nit = nt >> 1;
    f32x4 acc[8][4] = {};
    bf16x8 AX[4][2], BL[2][2], BH[2][2];

    stgB(0, 0);      stgA(0, 0);
    stgB(65536, 1);  stgA(65536, 1);
    asm volatile("s_waitcnt vmcnt(8)" ::: "memory");
    __builtin_amdgcn_s_barrier();
    __builtin_amdgcn_sched_barrier(0);
    #pragma unroll
    for (int m = 0; m < 4; ++m) {
        AX[m][0] = *(const bf16x8*)(LB + aRow[m] + cx0);
        AX[m][1] = *(const bf16x8*)(LB + aRow[m] + cx1);
    }
    #pragma unroll
    for (int n = 0; n < 2; ++n) {
        BL[n][0] = *(const bf16x8*)(LB + bRow[n]     + cx0);
        BL[n][1] = *(const bf16x8*)(LB + bRow[n]     + cx1);
    }
    #pragma unroll
    for (int n = 0; n < 2; ++n) {
        BH[n][0] = *(const bf16x8*)(LB + bRow[n + 2] + cx0);
        BH[n][1] = *(const bf16x8*)(LB + bRow[n + 2] + cx1);
    }
    asm volatile("s_waitcnt lgkmcnt(4)" ::: "memory");
    __builtin_amdgcn_sched_barrier(0);
    __builtin_amdgcn_s_setprio(1);
    #pragma unroll
    for (int m = 0; m < 4; ++m)
        #pragma unroll
        for (int n = 0; n < 2; ++n) {
            acc[m][n] = __builtin_amdgcn_mfma_f32_16x16x32_bf16(AX[m][0], BL[n][0], acc[m][n], 0, 0, 0);
            acc[m][n] = __builtin_amdgcn_mfma_f32_16x16x32_bf16(AX[m][1], BL[n][1], acc[m][n], 0, 0, 0);
        }
    __builtin_amdgcn_s_setprio(0);
    __builtin_amdgcn_s_barrier();

    for (int it = 0; it < nit; ++it) {
        int kA = 2 * it + 2; if (kA >= nt) kA = 0;
        int kB = 2 * it + 3; if (kB >= nt) kB = 0;
        #pragma unroll
        for (int db = 0; db < 2; ++db) {
            const int DBB = db * 65536;
            const char* Lb = LB + DBB;
            const char* Ln = LB + (DBB ^ 65536);
            const int kst = db ? kB : kA;
            const bool full = (db == 0) || (it < nit - 1);

            // ================= P_A =================
            stgB(DBB, kst);
            __builtin_amdgcn_s_setprio(1);
            #pragma unroll
            for (int m = 0; m < 4; ++m)
                #pragma unroll
                for (int n = 0; n < 2; ++n) {
                    acc[m][n + 2] = __builtin_amdgcn_mfma_f32_16x16x32_bf16(AX[m][0], BH[n][0], acc[m][n + 2], 0, 0, 0);
                    acc[m][n + 2] = __builtin_amdgcn_mfma_f32_16x16x32_bf16(AX[m][1], BH[n][1], acc[m][n + 2], 0, 0, 0);
                }
            __builtin_amdgcn_s_setprio(0);
            asm volatile("s_waitcnt vmcnt(4)" ::: "memory");
            __builtin_amdgcn_sched_barrier(0);
            #pragma unroll
            for (int m = 0; m < 4; ++m) {
                AX[m][0] = *(const bf16x8*)(Lb + aRow[m + 4] + cx0);
                AX[m][1] = *(const bf16x8*)(Lb + aRow[m + 4] + cx1);
            }
            asm volatile("s_waitcnt lgkmcnt(0)" ::: "memory");
            __builtin_amdgcn_sched_barrier(0);
            __builtin_amdgcn_s_setprio(1);
            #pragma unroll
            for (int m = 0; m < 4; ++m)
                #pragma unroll
                for (int n = 0; n < 2; ++n) {
                    acc[m + 4][n + 2] = __builtin_amdgcn_mfma_f32_16x16x32_bf16(AX[m][0], BH[n][0], acc[m + 4][n + 2], 0, 0, 0);
                    acc[m + 4][n + 2] = __builtin_amdgcn_mfma_f32_16x16x32_bf16(AX[m][1], BH[n][1], acc[m + 4][n + 2], 0, 0, 0);
                }
            __builtin_amdgcn_s_setprio(0);
            __builtin_amdgcn_s_barrier();

            // ================= P_B =================
            __builtin_amdgcn_s_setprio(1);
            #pragma unroll
            for (int m = 0; m < 4; ++m)
                #pragma unroll
                for (int n = 0; n < 2; ++n) {
                    acc[m + 4][n] = __builtin_amdgcn_mfma_f32_16x16x32_bf16(AX[m][0], BL[n][0], acc[m + 4][n], 0, 0, 0);
                    acc[m + 4][n] = __builtin_amdgcn_mfma_f32_16x16x32_bf16(AX[m][1], BL[n][1], acc[m + 4][n], 0, 0, 0);
                }
            __builtin_amdgcn_s_setprio(0);
            __builtin_amdgcn_sched_barrier(0);
            stgA(DBB, kst);
            if (full) {
                #pragma unroll
                for (int m = 0; m < 4; ++m) {
                    AX[m][0] = *(const bf16x8*)(Ln + aRow[m] + cx0);
                    AX[m][1] = *(const bf16x8*)(Ln + aRow[m] + cx1);
                }
                #pragma unroll
                for (int n = 0; n < 2; ++n) {
                    BL[n][0] = *(const bf16x8*)(Ln + bRow[n]     + cx0);
                    BL[n][1] = *(const bf16x8*)(Ln + bRow[n]     + cx1);
                }
                #pragma unroll
                for (int n = 0; n < 2; ++n) {
                    BH[n][0] = *(const bf16x8*)(Ln + bRow[n + 2] + cx0);
                    BH[n][1] = *(const bf16x8*)(Ln + bRow[n + 2] + cx1);
                }
                asm volatile("s_waitcnt lgkmcnt(4)" ::: "memory");
                __builtin_amdgcn_sched_barrier(0);
                __builtin_amdgcn_s_setprio(1);
                #pragma unroll
                for (int m = 0; m < 4; ++m)
                    #pragma unroll
                    for (int n = 0; n < 2; ++n) {
                        acc[m][n] = __builtin_amdgcn_mfma_f32_16x16x32_bf16(AX[m][0], BL[n][0], acc[m][n], 0, 0, 0);
                        acc[m][n] = __builtin_amdgcn_mfma_f32_16x16x32_bf16(AX[m][1], BL[n][1], acc[m][n], 0, 0, 0);
                    }
                __builtin_amdgcn_s_setprio(0);
            }
            __builtin_amdgcn_s_barrier();
        }
    }

    asm volatile("s_waitcnt vmcnt(0)" ::: "memory");
    __builtin_amdgcn_s_barrier();

    const int lg = l >> 4;
    const long wrow = rowBase + hm * 128;
    const long wcol = colBase + q * 64;
    char* ep = LB + w * 16384;

    if (EPI == 2) {
        #pragma unroll
        for (int mh = 0; mh < 2; ++mh) {
            #pragma unroll
            for (int m = 0; m < 4; ++m) {
                #pragma unroll
                for (int n = 0; n < 4; ++n) {
                    f32x4 v = acc[mh * 4 + m][n];
                    #pragma unroll
                    for (int r = 0; r < 4; ++r) {
                        int rowr = m * 16 + lg * 4 + r;
                        int chnk = (n * 4 + (lr >> 2)) ^ (rowr & 7);
                        *(float*)(ep + rowr * 256 + chnk * 16 + (lr & 3) * 4) = v[r];
                    }
                }
            }
            asm volatile("s_waitcnt lgkmcnt(0)" ::: "memory");
            #pragma unroll
            for (int i = 0; i < 16; ++i) {
                int rr = i * 4 + (l >> 4);
                float4 lv = *(float4*)(ep + rr * 256 + (((l & 15) ^ (rr & 7)) * 16));
                long off = (wrow + mh * 64 + rr) * N + wcol + (l & 15) * 4;
                float4 rv = *(const float4*)(res + off);
                lv.x += rv.x; lv.y += rv.y; lv.z += rv.z; lv.w += rv.w;
                *(float4*)((float*)C + off) = lv;
            }
            if (mh == 0) { asm volatile("s_waitcnt lgkmcnt(0) vmcnt(0)" ::: "memory"); }
        }
    } else {
        #pragma unroll
        for (int m = 0; m < 8; ++m) {
            #pragma unroll
            for (int n = 0; n < 4; ++n) {
                f32x4 v = acc[m][n];
                #pragma unroll
                for (int r = 0; r < 4; ++r) {
                    int rowr = m * 16 + lg * 4 + r;
                    int chnk = (n * 2 + (lr >> 3)) ^ (rowr & 7);
                    float val = (EPI == 1) ? fmaxf(v[r], 0.f) : v[r];
                    *(bf16*)(ep + rowr * 128 + chnk * 16 + (lr & 7) * 2) = (bf16)val;
                }
            }
        }
        asm volatile("s_waitcnt lgkmcnt(0)" ::: "memory");
        #pragma unroll
        for (int i = 0; i < 16; ++i) {
            int rr = i * 8 + (l >> 3);
            uint4 lv = *(uint4*)(ep + rr * 128 + (((l & 7) ^ (rr & 7)) * 16));
            *(uint4*)((bf16*)C + (wrow + rr) * N + wcol + (l & 7) * 8) = lv;
        }
    }
}

extern "C" void kernel_launch(void* const* d_in, const int* in_sizes, int n_in,
                              void* d_out, int out_size, void* d_ws, size_t ws_size,
                              hipStream_t stream) {
    const float* x      = (const float*)d_in[0];
    const float* W_in   = (const float*)d_in[1];
    const float* cw     = (const float*)d_in[2];
    const float* cb     = (const float*)d_in[3];
    const float* W_out  = (const float*)d_in[4];
    const float* W_mlp1 = (const float*)d_in[5];
    const float* W_mlp2 = (const float*)d_in[6];
    float* out = (float*)d_out;

    char* ws  = (char*)d_ws;
    bf16* wW  = (bf16*)(ws);                    // 33.55 MB (max bf16 weight)
    bf16* h   = (bf16*)(ws + 33554432);         // 33.55 MB (h / h2)
    bf16* xz  = (bf16*)(ws + 67108864);         // 134.2 MB (xz / m1)
    float* x2 = (float*)(ws + 201326592);       // 67.1 MB
    bf16* y   = xz + D_INNER;                   // in-place over z half, lda = 8192
    bf16* m1  = xz;

    dim3 blk(256);
    dim3 gblk(512);

    // mamba branch
    f2b_kernel<<<dim3(8192), blk, 0, stream>>>(W_in, wW, 16777216/8);
    rmsnorm_kernel<<<dim3(ROWS), blk, 0, stream>>>(x, h);
    gemm_w4<0><<<dim3(1024), blk, 0, stream>>>(h, D_MODEL, wW, xz, 2*D_INNER, D_MODEL, 32);
    conv_gate_kernel<<<dim3(16384), blk, 0, stream>>>(xz, cw, cb);
    f2b_kernel<<<dim3(4096), blk, 0, stream>>>(W_out, wW, 8388608/8);
    gemm_bt<2><<<dim3(256), gblk, 0, stream>>>(y, 2*D_INNER, wW, x2, x, D_MODEL, D_INNER, 8);

    // mlp branch
    rmsnorm_kernel<<<dim3(ROWS), blk, 0, stream>>>(x2, h);
    f2b_kernel<<<dim3(8192), blk, 0, stream>>>(W_mlp1, wW, 16777216/8);
    gemm_w4<1><<<dim3(1024), blk, 0, stream>>>(h, D_MODEL, wW, m1, 4*D_MODEL, D_MODEL, 32);
    f2b_kernel<<<dim3(8192), blk, 0, stream>>>(W_mlp2, wW, 16777216/8);
    gemm_bt<2><<<dim3(256), gblk, 0, stream>>>(m1, 4*D_MODEL, wW, out, x2, D_MODEL, 4*D_MODEL, 8);
}

// Round 11
// 961.398 us; speedup vs baseline: 3.7455x; 1.2067x over previous
//
#include <hip/hip_runtime.h>
#include <hip/hip_bf16.h>

typedef __bf16 bf16;
typedef __bf16 bf16x8 __attribute__((ext_vector_type(8)));
typedef float f32x4 __attribute__((ext_vector_type(4)));

#define D_MODEL 2048
#define D_INNER 4096
#define ROWS    8192   // B*T

__device__ __forceinline__ void gload_lds16(const void* g, void* l) {
    __builtin_amdgcn_global_load_lds(
        (const __attribute__((address_space(1))) void*)g,
        (__attribute__((address_space(3))) void*)l, 16, 0, 0);
}

// ---------------- device bodies (shared by merged kernels) ----------------
__device__ __forceinline__ void f2b_body(const float* __restrict__ in,
                                         bf16* __restrict__ out, int i, int n8) {
    if (i >= n8) return;
    long base = (long)i * 8;
    float4 a = *(const float4*)(in + base);
    float4 b = *(const float4*)(in + base + 4);
    bf16x8 o;
    o[0] = (bf16)a.x; o[1] = (bf16)a.y; o[2] = (bf16)a.z; o[3] = (bf16)a.w;
    o[4] = (bf16)b.x; o[5] = (bf16)b.y; o[6] = (bf16)b.z; o[7] = (bf16)b.w;
    *(bf16x8*)(out + base) = o;
}

__device__ __forceinline__ void rmsnorm_body(const float* __restrict__ x,
                                             bf16* __restrict__ h, int row) {
    const float* xr = x + (long)row * D_MODEL;
    float4 v0 = ((const float4*)xr)[threadIdx.x * 2];
    float4 v1 = ((const float4*)xr)[threadIdx.x * 2 + 1];
    float ss = v0.x*v0.x + v0.y*v0.y + v0.z*v0.z + v0.w*v0.w
             + v1.x*v1.x + v1.y*v1.y + v1.z*v1.z + v1.w*v1.w;
    #pragma unroll
    for (int o = 32; o; o >>= 1) ss += __shfl_xor(ss, o, 64);
    __shared__ float red[4];
    if ((threadIdx.x & 63) == 0) red[threadIdx.x >> 6] = ss;
    __syncthreads();
    float tot = red[0] + red[1] + red[2] + red[3];
    float scale = 45.254834f / fmaxf(sqrtf(tot), 1e-12f);  // sqrt(2048)/max(||x||,eps)
    bf16x8 o;
    o[0] = (bf16)(v0.x*scale); o[1] = (bf16)(v0.y*scale);
    o[2] = (bf16)(v0.z*scale); o[3] = (bf16)(v0.w*scale);
    o[4] = (bf16)(v1.x*scale); o[5] = (bf16)(v1.y*scale);
    o[6] = (bf16)(v1.z*scale); o[7] = (bf16)(v1.w*scale);
    *(bf16x8*)(h + (long)row * D_MODEL + threadIdx.x * 8) = o;
}

__device__ __forceinline__ void conv_body(bf16* __restrict__ xz,
                                          const float* __restrict__ cw,
                                          const float* __restrict__ cb, int idx) {
    const int c8  = idx & 511;
    const int row = idx >> 9;
    const int t   = row & 2047;                        // position within batch (T=2048)
    const int c0  = c8 * 8;
    float acc[8];
    float wv[8][4];
    #pragma unroll
    for (int e = 0; e < 8; ++e) {
        float4 f = ((const float4*)cw)[c0 + e];
        wv[e][0] = f.x; wv[e][1] = f.y; wv[e][2] = f.z; wv[e][3] = f.w;
        acc[e] = cb[c0 + e];
    }
    #pragma unroll
    for (int j = 0; j < 4; ++j) {
        if (t + j - 3 >= 0) {
            bf16x8 xv = *(const bf16x8*)(xz + (long)(row + j - 3) * (2*D_INNER) + c0);
            #pragma unroll
            for (int e = 0; e < 8; ++e) acc[e] += (float)xv[e] * wv[e][j];
        }
    }
    bf16* zp = xz + (long)row * (2*D_INNER) + D_INNER + c0;
    bf16x8 zv = *(const bf16x8*)zp;
    bf16x8 yv;
    #pragma unroll
    for (int e = 0; e < 8; ++e) {
        float xc = acc[e];
        float s1 = xc / (1.f + __expf(-xc));
        float z  = (float)zv[e];
        float s2 = z / (1.f + __expf(-z));
        yv[e] = (bf16)(s1 * s2);
    }
    *(bf16x8*)zp = yv;
}

// ---------------- merged elementwise kernels ----------------
// rmsnorm (blocks [0,8192)) + f2b (blocks [8192, 8192+n8/256))
__global__ __launch_bounds__(256) void prep_kernel(const float* __restrict__ x,
                                                   bf16* __restrict__ h,
                                                   const float* __restrict__ w,
                                                   bf16* __restrict__ wOut, int n8) {
    if ((int)blockIdx.x < ROWS) rmsnorm_body(x, h, blockIdx.x);
    else f2b_body(w, wOut, (blockIdx.x - ROWS) * 256 + threadIdx.x, n8);
}

// conv_gate (blocks [0,16384)) + f2b W_out (blocks [16384, 16384+4096))
__global__ __launch_bounds__(256) void convf2b_kernel(bf16* __restrict__ xz,
                                                      const float* __restrict__ cw,
                                                      const float* __restrict__ cb,
                                                      const float* __restrict__ w,
                                                      bf16* __restrict__ wOut, int n8) {
    if ((int)blockIdx.x < 16384) conv_body(xz, cw, cb, blockIdx.x * 256 + threadIdx.x);
    else f2b_body(w, wOut, (blockIdx.x - 16384) * 256 + threadIdx.x, n8);
}

__global__ __launch_bounds__(256) void f2b_kernel(const float* __restrict__ in,
                                                  bf16* __restrict__ out, int n8) {
    f2b_body(in, out, blockIdx.x * 256 + threadIdx.x, n8);
}

// ---------------- bf16 GEMM v7 (proven): C = A @ B^T (+ epilogue) ----------
// 256x256 tile, BK=64, 512 threads = 8 waves (2M x 4N), per-wave 128x64.
// 2 dbuf x 64KB, XOR chunk swizzle (inverse-swizzled global source),
// 2 super-phases/K-tile with pipelined frag reads, counted vmcnt, T5 setprio.
// XCD map: gx==32 -> 2D 8x16 region per XCD (L2 working set 36->24MB);
// else chunked-linear (gx==8 regions already compact). Both bijective.
// EPI: 0 = store bf16, 1 = relu+store bf16, 2 = fp32 res-add + store fp32
template<int EPI>
__global__ __launch_bounds__(512, 2) void gemm_bt(
        const bf16* __restrict__ A, long lda,
        const bf16* __restrict__ B,
        void* __restrict__ C, const float* __restrict__ res,
        int N, int K, int gx) {
    __shared__ __align__(16) char LB[131072];
    const int tid = threadIdx.x;
    const int w   = tid >> 6;
    const int l   = tid & 63;
    const int lr  = l & 15;

    // XCD-aware block mapping (bijective)
    int bx, by;
    if (gx == 32) {
        const int xcd = blockIdx.x & 7, i = blockIdx.x >> 3;   // i in [0,128)
        by = (xcd >> 1) * 8 + (i >> 4);
        bx = (xcd & 1) * 16 + (i & 15);
    } else {
        const int qq = gridDim.x >> 3;
        const int sw = (blockIdx.x & 7) * qq + (blockIdx.x >> 3);
        bx = sw % gx; by = sw / gx;
    }
    const long rowBase = (long)by * 256;
    const long colBase = (long)bx * 256;

    const int srow = w * 8 + (l >> 3);
    const int schk = (l & 7) ^ ((l >> 3) & 7);
    const bf16* aSrc = A + (rowBase + srow) * lda + schk * 8;
    const bf16* bSrc = B + (colBase + srow) * (long)K + schk * 8;
    const long lda64 = 64 * lda;
    const long ldb64 = 64 * (long)K;
    const int  w1024 = w * 1024;

    auto stgA = [&](int DBB, int kt) {
        const bf16* s = aSrc + (long)kt * 64;
        gload_lds16(s,            LB + DBB +     0 + w1024);
        gload_lds16(s +   lda64,  LB + DBB +  8192 + w1024);
        gload_lds16(s + 2*lda64,  LB + DBB + 16384 + w1024);
        gload_lds16(s + 3*lda64,  LB + DBB + 24576 + w1024);
    };
    auto stgB = [&](int DBB, int kt) {
        const bf16* s = bSrc + (long)kt * 64;
        gload_lds16(s,            LB + DBB + 32768 + w1024);
        gload_lds16(s +   ldb64,  LB + DBB + 40960 + w1024);
        gload_lds16(s + 2*ldb64,  LB + DBB + 49152 + w1024);
        gload_lds16(s + 3*ldb64,  LB + DBB + 57344 + w1024);
    };

    const int cx0 = (((l >> 4)    ) ^ (l & 7)) << 4;
    const int cx1 = (((l >> 4) + 4) ^ (l & 7)) << 4;
    const int hm = w >> 2;
    const int q  = w & 3;
    int aRow[8], bRow[4];
    #pragma unroll
    for (int m = 0; m < 8; ++m) aRow[m] = hm * 16384 + (m * 16 + lr) * 128;
    #pragma unroll
    for (int n = 0; n < 4; ++n)
        bRow[n] = 32768 + (q >> 1) * 16384 + ((q & 1) * 64 + n * 16 + lr) * 128;

    const int nt  = K >> 6;
    const int nit = nt >> 1;
    f32x4 acc[8][4] = {};
    bf16x8 AX[4][2], BL[2][2], BH[2][2];

    stgB(0, 0);      stgA(0, 0);
    stgB(65536, 1);  stgA(65536, 1);
    asm volatile("s_waitcnt vmcnt(8)" ::: "memory");
    __builtin_amdgcn_s_barrier();
    __builtin_amdgcn_sched_barrier(0);
    #pragma unroll
    for (int m = 0; m < 4; ++m) {
        AX[m][0] = *(const bf16x8*)(LB + aRow[m] + cx0);
        AX[m][1] = *(const bf16x8*)(LB + aRow[m] + cx1);
    }
    #pragma unroll
    for (int n = 0; n < 2; ++n) {
        BL[n][0] = *(const bf16x8*)(LB + bRow[n]     + cx0);
        BL[n][1] = *(const bf16x8*)(LB + bRow[n]     + cx1);
    }
    #pragma unroll
    for (int n = 0; n < 2; ++n) {
        BH[n][0] = *(const bf16x8*)(LB + bRow[n + 2] + cx0);
        BH[n][1] = *(const bf16x8*)(LB + bRow[n + 2] + cx1);
    }
    asm volatile("s_waitcnt lgkmcnt(4)" ::: "memory");
    __builtin_amdgcn_sched_barrier(0);
    __builtin_amdgcn_s_setprio(1);
    #pragma unroll
    for (int m = 0; m < 4; ++m)
        #pragma unroll
        for (int n = 0; n < 2; ++n) {
            acc[m][n] = __builtin_amdgcn_mfma_f32_16x16x32_bf16(AX[m][0], BL[n][0], acc[m][n], 0, 0, 0);
            acc[m][n] = __builtin_amdgcn_mfma_f32_16x16x32_bf16(AX[m][1], BL[n][1], acc[m][n], 0, 0, 0);
        }
    __builtin_amdgcn_s_setprio(0);
    __builtin_amdgcn_s_barrier();

    for (int it = 0; it < nit; ++it) {
        int kA = 2 * it + 2; if (kA >= nt) kA = 0;
        int kB = 2 * it + 3; if (kB >= nt) kB = 0;
        #pragma unroll
        for (int db = 0; db < 2; ++db) {
            const int DBB = db * 65536;
            const char* Lb = LB + DBB;
            const char* Ln = LB + (DBB ^ 65536);
            const int kst = db ? kB : kA;
            const bool full = (db == 0) || (it < nit - 1);

            // ================= P_A =================
            stgB(DBB, kst);
            __builtin_amdgcn_s_setprio(1);
            #pragma unroll
            for (int m = 0; m < 4; ++m)
                #pragma unroll
                for (int n = 0; n < 2; ++n) {
                    acc[m][n + 2] = __builtin_amdgcn_mfma_f32_16x16x32_bf16(AX[m][0], BH[n][0], acc[m][n + 2], 0, 0, 0);
                    acc[m][n + 2] = __builtin_amdgcn_mfma_f32_16x16x32_bf16(AX[m][1], BH[n][1], acc[m][n + 2], 0, 0, 0);
                }
            __builtin_amdgcn_s_setprio(0);
            asm volatile("s_waitcnt vmcnt(4)" ::: "memory");
            __builtin_amdgcn_sched_barrier(0);
            #pragma unroll
            for (int m = 0; m < 4; ++m) {
                AX[m][0] = *(const bf16x8*)(Lb + aRow[m + 4] + cx0);
                AX[m][1] = *(const bf16x8*)(Lb + aRow[m + 4] + cx1);
            }
            asm volatile("s_waitcnt lgkmcnt(0)" ::: "memory");
            __builtin_amdgcn_sched_barrier(0);
            __builtin_amdgcn_s_setprio(1);
            #pragma unroll
            for (int m = 0; m < 4; ++m)
                #pragma unroll
                for (int n = 0; n < 2; ++n) {
                    acc[m + 4][n + 2] = __builtin_amdgcn_mfma_f32_16x16x32_bf16(AX[m][0], BH[n][0], acc[m + 4][n + 2], 0, 0, 0);
                    acc[m + 4][n + 2] = __builtin_amdgcn_mfma_f32_16x16x32_bf16(AX[m][1], BH[n][1], acc[m + 4][n + 2], 0, 0, 0);
                }
            __builtin_amdgcn_s_setprio(0);
            __builtin_amdgcn_s_barrier();

            // ================= P_B =================
            __builtin_amdgcn_s_setprio(1);
            #pragma unroll
            for (int m = 0; m < 4; ++m)
                #pragma unroll
                for (int n = 0; n < 2; ++n) {
                    acc[m + 4][n] = __builtin_amdgcn_mfma_f32_16x16x32_bf16(AX[m][0], BL[n][0], acc[m + 4][n], 0, 0, 0);
                    acc[m + 4][n] = __builtin_amdgcn_mfma_f32_16x16x32_bf16(AX[m][1], BL[n][1], acc[m + 4][n], 0, 0, 0);
                }
            __builtin_amdgcn_s_setprio(0);
            __builtin_amdgcn_sched_barrier(0);
            stgA(DBB, kst);
            if (full) {
                #pragma unroll
                for (int m = 0; m < 4; ++m) {
                    AX[m][0] = *(const bf16x8*)(Ln + aRow[m] + cx0);
                    AX[m][1] = *(const bf16x8*)(Ln + aRow[m] + cx1);
                }
                #pragma unroll
                for (int n = 0; n < 2; ++n) {
                    BL[n][0] = *(const bf16x8*)(Ln + bRow[n]     + cx0);
                    BL[n][1] = *(const bf16x8*)(Ln + bRow[n]     + cx1);
                }
                #pragma unroll
                for (int n = 0; n < 2; ++n) {
                    BH[n][0] = *(const bf16x8*)(Ln + bRow[n + 2] + cx0);
                    BH[n][1] = *(const bf16x8*)(Ln + bRow[n + 2] + cx1);
                }
                asm volatile("s_waitcnt lgkmcnt(4)" ::: "memory");
                __builtin_amdgcn_sched_barrier(0);
                __builtin_amdgcn_s_setprio(1);
                #pragma unroll
                for (int m = 0; m < 4; ++m)
                    #pragma unroll
                    for (int n = 0; n < 2; ++n) {
                        acc[m][n] = __builtin_amdgcn_mfma_f32_16x16x32_bf16(AX[m][0], BL[n][0], acc[m][n], 0, 0, 0);
                        acc[m][n] = __builtin_amdgcn_mfma_f32_16x16x32_bf16(AX[m][1], BL[n][1], acc[m][n], 0, 0, 0);
                    }
                __builtin_amdgcn_s_setprio(0);
            }
            __builtin_amdgcn_s_barrier();
        }
    }

    asm volatile("s_waitcnt vmcnt(0)" ::: "memory");
    __builtin_amdgcn_s_barrier();

    // epilogue: per-wave private 16KB LDS region, chunk-XOR swizzle
    const int lg = l >> 4;
    const long wrow = rowBase + hm * 128;
    const long wcol = colBase + q * 64;
    char* ep = LB + w * 16384;

    if (EPI == 2) {
        #pragma unroll
        for (int mh = 0; mh < 2; ++mh) {
            #pragma unroll
            for (int m = 0; m < 4; ++m) {
                #pragma unroll
                for (int n = 0; n < 4; ++n) {
                    f32x4 v = acc[mh * 4 + m][n];
                    #pragma unroll
                    for (int r = 0; r < 4; ++r) {
                        int rowr = m * 16 + lg * 4 + r;
                        int chnk = (n * 4 + (lr >> 2)) ^ (rowr & 7);
                        *(float*)(ep + rowr * 256 + chnk * 16 + (lr & 3) * 4) = v[r];
                    }
                }
            }
            asm volatile("s_waitcnt lgkmcnt(0)" ::: "memory");
            #pragma unroll
            for (int i = 0; i < 16; ++i) {
                int rr = i * 4 + (l >> 4);
                float4 lv = *(float4*)(ep + rr * 256 + (((l & 15) ^ (rr & 7)) * 16));
                long off = (wrow + mh * 64 + rr) * N + wcol + (l & 15) * 4;
                float4 rv = *(const float4*)(res + off);
                lv.x += rv.x; lv.y += rv.y; lv.z += rv.z; lv.w += rv.w;
                *(float4*)((float*)C + off) = lv;
            }
            if (mh == 0) { asm volatile("s_waitcnt lgkmcnt(0) vmcnt(0)" ::: "memory"); }
        }
    } else {
        #pragma unroll
        for (int m = 0; m < 8; ++m) {
            #pragma unroll
            for (int n = 0; n < 4; ++n) {
                f32x4 v = acc[m][n];
                #pragma unroll
                for (int r = 0; r < 4; ++r) {
                    int rowr = m * 16 + lg * 4 + r;
                    int chnk = (n * 2 + (lr >> 3)) ^ (rowr & 7);
                    float val = (EPI == 1) ? fmaxf(v[r], 0.f) : v[r];
                    *(bf16*)(ep + rowr * 128 + chnk * 16 + (lr & 7) * 2) = (bf16)val;
                }
            }
        }
        asm volatile("s_waitcnt lgkmcnt(0)" ::: "memory");
        #pragma unroll
        for (int i = 0; i < 16; ++i) {
            int rr = i * 8 + (l >> 3);
            uint4 lv = *(uint4*)(ep + rr * 128 + (((l & 7) ^ (rr & 7)) * 16));
            *(uint4*)((bf16*)C + (wrow + rr) * N + wcol + (l & 7) * 8) = lv;
        }
    }
}

extern "C" void kernel_launch(void* const* d_in, const int* in_sizes, int n_in,
                              void* d_out, int out_size, void* d_ws, size_t ws_size,
                              hipStream_t stream) {
    const float* x      = (const float*)d_in[0];
    const float* W_in   = (const float*)d_in[1];
    const float* cw     = (const float*)d_in[2];
    const float* cb     = (const float*)d_in[3];
    const float* W_out  = (const float*)d_in[4];
    const float* W_mlp1 = (const float*)d_in[5];
    const float* W_mlp2 = (const float*)d_in[6];
    float* out = (float*)d_out;

    char* ws  = (char*)d_ws;
    bf16* wW  = (bf16*)(ws);                    // 33.55 MB (max bf16 weight)
    bf16* h   = (bf16*)(ws + 33554432);         // 33.55 MB (h / h2)
    bf16* xz  = (bf16*)(ws + 67108864);         // 134.2 MB (xz / m1)
    float* x2 = (float*)(ws + 201326592);       // 67.1 MB
    bf16* y   = xz + D_INNER;                   // in-place over z half, lda = 8192
    bf16* m1  = xz;

    dim3 blk(256);
    dim3 gblk(512);

    // mamba branch
    prep_kernel<<<dim3(ROWS + 8192), blk, 0, stream>>>(x, h, W_in, wW, 16777216/8);
    gemm_bt<0><<<dim3(1024), gblk, 0, stream>>>(h, D_MODEL, wW, xz, nullptr, 2*D_INNER, D_MODEL, 32);
    convf2b_kernel<<<dim3(16384 + 4096), blk, 0, stream>>>(xz, cw, cb, W_out, wW, 8388608/8);
    gemm_bt<2><<<dim3(256), gblk, 0, stream>>>(y, 2*D_INNER, wW, x2, x, D_MODEL, D_INNER, 8);

    // mlp branch
    prep_kernel<<<dim3(ROWS + 8192), blk, 0, stream>>>(x2, h, W_mlp1, wW, 16777216/8);
    gemm_bt<1><<<dim3(1024), gblk, 0, stream>>>(h, D_MODEL, wW, m1, nullptr, 4*D_MODEL, D_MODEL, 32);
    f2b_kernel<<<dim3(8192), blk, 0, stream>>>(W_mlp2, wW, 16777216/8);
    gemm_bt<2><<<dim3(256), gblk, 0, stream>>>(m1, 4*D_MODEL, wW, out, x2, D_MODEL, 4*D_MODEL, 8);
}

// Round 12
// 958.845 us; speedup vs baseline: 3.7555x; 1.0027x over previous
//
#include <hip/hip_runtime.h>
#include <hip/hip_bf16.h>

typedef __bf16 bf16;
typedef __bf16 bf16x8 __attribute__((ext_vector_type(8)));
typedef float f32x4 __attribute__((ext_vector_type(4)));

#define D_MODEL 2048
#define D_INNER 4096
#define ROWS    8192   // B*T

__device__ __forceinline__ void gload_lds16(const void* g, void* l) {
    __builtin_amdgcn_global_load_lds(
        (const __attribute__((address_space(1))) void*)g,
        (__attribute__((address_space(3))) void*)l, 16, 0, 0);
}

// ---------------- device bodies (shared by merged kernels) ----------------
__device__ __forceinline__ void f2b_body(const float* __restrict__ in,
                                         bf16* __restrict__ out, int i, int n8) {
    if (i >= n8) return;
    long base = (long)i * 8;
    float4 a = *(const float4*)(in + base);
    float4 b = *(const float4*)(in + base + 4);
    bf16x8 o;
    o[0] = (bf16)a.x; o[1] = (bf16)a.y; o[2] = (bf16)a.z; o[3] = (bf16)a.w;
    o[4] = (bf16)b.x; o[5] = (bf16)b.y; o[6] = (bf16)b.z; o[7] = (bf16)b.w;
    *(bf16x8*)(out + base) = o;
}

__device__ __forceinline__ void rmsnorm_body(const float* __restrict__ x,
                                             bf16* __restrict__ h, int row) {
    const float* xr = x + (long)row * D_MODEL;
    float4 v0 = ((const float4*)xr)[threadIdx.x * 2];
    float4 v1 = ((const float4*)xr)[threadIdx.x * 2 + 1];
    float ss = v0.x*v0.x + v0.y*v0.y + v0.z*v0.z + v0.w*v0.w
             + v1.x*v1.x + v1.y*v1.y + v1.z*v1.z + v1.w*v1.w;
    #pragma unroll
    for (int o = 32; o; o >>= 1) ss += __shfl_xor(ss, o, 64);
    __shared__ float red[4];
    if ((threadIdx.x & 63) == 0) red[threadIdx.x >> 6] = ss;
    __syncthreads();
    float tot = red[0] + red[1] + red[2] + red[3];
    float scale = 45.254834f / fmaxf(sqrtf(tot), 1e-12f);  // sqrt(2048)/max(||x||,eps)
    bf16x8 o;
    o[0] = (bf16)(v0.x*scale); o[1] = (bf16)(v0.y*scale);
    o[2] = (bf16)(v0.z*scale); o[3] = (bf16)(v0.w*scale);
    o[4] = (bf16)(v1.x*scale); o[5] = (bf16)(v1.y*scale);
    o[6] = (bf16)(v1.z*scale); o[7] = (bf16)(v1.w*scale);
    *(bf16x8*)(h + (long)row * D_MODEL + threadIdx.x * 8) = o;
}

__device__ __forceinline__ void conv_body(bf16* __restrict__ xz,
                                          const float* __restrict__ cw,
                                          const float* __restrict__ cb, int idx) {
    const int c8  = idx & 511;
    const int row = idx >> 9;
    const int t   = row & 2047;                        // position within batch (T=2048)
    const int c0  = c8 * 8;
    float acc[8];
    float wv[8][4];
    #pragma unroll
    for (int e = 0; e < 8; ++e) {
        float4 f = ((const float4*)cw)[c0 + e];
        wv[e][0] = f.x; wv[e][1] = f.y; wv[e][2] = f.z; wv[e][3] = f.w;
        acc[e] = cb[c0 + e];
    }
    #pragma unroll
    for (int j = 0; j < 4; ++j) {
        if (t + j - 3 >= 0) {
            bf16x8 xv = *(const bf16x8*)(xz + (long)(row + j - 3) * (2*D_INNER) + c0);
            #pragma unroll
            for (int e = 0; e < 8; ++e) acc[e] += (float)xv[e] * wv[e][j];
        }
    }
    bf16* zp = xz + (long)row * (2*D_INNER) + D_INNER + c0;
    bf16x8 zv = *(const bf16x8*)zp;
    bf16x8 yv;
    #pragma unroll
    for (int e = 0; e < 8; ++e) {
        float xc = acc[e];
        float s1 = xc / (1.f + __expf(-xc));
        float z  = (float)zv[e];
        float s2 = z / (1.f + __expf(-z));
        yv[e] = (bf16)(s1 * s2);
    }
    *(bf16x8*)zp = yv;
}

// ---------------- merged elementwise kernels ----------------
// rmsnorm (blocks [0,8192)) + f2b (blocks [8192, 8192+n8/256))
__global__ __launch_bounds__(256) void prep_kernel(const float* __restrict__ x,
                                                   bf16* __restrict__ h,
                                                   const float* __restrict__ w,
                                                   bf16* __restrict__ wOut, int n8) {
    if ((int)blockIdx.x < ROWS) rmsnorm_body(x, h, blockIdx.x);
    else f2b_body(w, wOut, (blockIdx.x - ROWS) * 256 + threadIdx.x, n8);
}

// conv_gate (blocks [0,16384)) + f2b W_out (blocks [16384, 16384+4096))
__global__ __launch_bounds__(256) void convf2b_kernel(bf16* __restrict__ xz,
                                                      const float* __restrict__ cw,
                                                      const float* __restrict__ cb,
                                                      const float* __restrict__ w,
                                                      bf16* __restrict__ wOut, int n8) {
    if ((int)blockIdx.x < 16384) conv_body(xz, cw, cb, blockIdx.x * 256 + threadIdx.x);
    else f2b_body(w, wOut, (blockIdx.x - 16384) * 256 + threadIdx.x, n8);
}

__global__ __launch_bounds__(256) void f2b_kernel(const float* __restrict__ in,
                                                  bf16* __restrict__ out, int n8) {
    f2b_body(in, out, blockIdx.x * 256 + threadIdx.x, n8);
}

// ---------------- bf16 GEMM v10: C = A @ B^T (+ epilogue) ------------------
// v7 core (256x256 tile, BK=64, 8 waves 2Mx4N, 2 dbuf x 64KB, XOR chunk
// swizzle, 2 super-phases/K-tile, counted vmcnt, T5 setprio, 2D XCD map)
// with two latency fixes:
//  (1) refill reads interleaved into MFMA clusters at register death:
//      q2's m-iteration ends with AX[m] <- A1(t); q4's with AX[m] <- A0(t+1).
//      Reads drain under the remaining MFMAs -> lgkmcnt nearly free.
//  (2) vmcnt(4) moved from before the A1 reads to after q3 (just before the
//      P_A-end barrier): A1 is tile-t data (entry barrier guarantees it);
//      the consumers vmcnt protects sit after the barrier either way ->
//      stgA(t+1) gets ~600 more cycles of slack.
// Race ledger unchanged from v7.
// EPI: 0 = store bf16, 1 = relu+store bf16, 2 = fp32 res-add + store fp32
template<int EPI>
__global__ __launch_bounds__(512, 2) void gemm_bt(
        const bf16* __restrict__ A, long lda,
        const bf16* __restrict__ B,
        void* __restrict__ C, const float* __restrict__ res,
        int N, int K, int gx) {
    __shared__ __align__(16) char LB[131072];
    const int tid = threadIdx.x;
    const int w   = tid >> 6;
    const int l   = tid & 63;
    const int lr  = l & 15;

    // XCD-aware block mapping (bijective)
    int bx, by;
    if (gx == 32) {
        const int xcd = blockIdx.x & 7, i = blockIdx.x >> 3;   // i in [0,128)
        by = (xcd >> 1) * 8 + (i >> 4);
        bx = (xcd & 1) * 16 + (i & 15);
    } else {
        const int qq = gridDim.x >> 3;
        const int sw = (blockIdx.x & 7) * qq + (blockIdx.x >> 3);
        bx = sw % gx; by = sw / gx;
    }
    const long rowBase = (long)by * 256;
    const long colBase = (long)bx * 256;

    const int srow = w * 8 + (l >> 3);
    const int schk = (l & 7) ^ ((l >> 3) & 7);
    const bf16* aSrc = A + (rowBase + srow) * lda + schk * 8;
    const bf16* bSrc = B + (colBase + srow) * (long)K + schk * 8;
    const long lda64 = 64 * lda;
    const long ldb64 = 64 * (long)K;
    const int  w1024 = w * 1024;

    auto stgA = [&](int DBB, int kt) {
        const bf16* s = aSrc + (long)kt * 64;
        gload_lds16(s,            LB + DBB +     0 + w1024);
        gload_lds16(s +   lda64,  LB + DBB +  8192 + w1024);
        gload_lds16(s + 2*lda64,  LB + DBB + 16384 + w1024);
        gload_lds16(s + 3*lda64,  LB + DBB + 24576 + w1024);
    };
    auto stgB = [&](int DBB, int kt) {
        const bf16* s = bSrc + (long)kt * 64;
        gload_lds16(s,            LB + DBB + 32768 + w1024);
        gload_lds16(s +   ldb64,  LB + DBB + 40960 + w1024);
        gload_lds16(s + 2*ldb64,  LB + DBB + 49152 + w1024);
        gload_lds16(s + 3*ldb64,  LB + DBB + 57344 + w1024);
    };

    const int cx0 = (((l >> 4)    ) ^ (l & 7)) << 4;
    const int cx1 = (((l >> 4) + 4) ^ (l & 7)) << 4;
    const int hm = w >> 2;
    const int q  = w & 3;
    int aRow[8], bRow[4];
    #pragma unroll
    for (int m = 0; m < 8; ++m) aRow[m] = hm * 16384 + (m * 16 + lr) * 128;
    #pragma unroll
    for (int n = 0; n < 4; ++n)
        bRow[n] = 32768 + (q >> 1) * 16384 + ((q & 1) * 64 + n * 16 + lr) * 128;

    const int nt  = K >> 6;
    const int nit = nt >> 1;
    f32x4 acc[8][4] = {};
    bf16x8 AX[4][2], BL[2][2], BH[2][2];

    stgB(0, 0);      stgA(0, 0);
    stgB(65536, 1);  stgA(65536, 1);
    asm volatile("s_waitcnt vmcnt(8)" ::: "memory");
    __builtin_amdgcn_s_barrier();
    __builtin_amdgcn_sched_barrier(0);
    #pragma unroll
    for (int m = 0; m < 4; ++m) {
        AX[m][0] = *(const bf16x8*)(LB + aRow[m] + cx0);
        AX[m][1] = *(const bf16x8*)(LB + aRow[m] + cx1);
    }
    #pragma unroll
    for (int n = 0; n < 2; ++n) {
        BL[n][0] = *(const bf16x8*)(LB + bRow[n]     + cx0);
        BL[n][1] = *(const bf16x8*)(LB + bRow[n]     + cx1);
    }
    #pragma unroll
    for (int n = 0; n < 2; ++n) {
        BH[n][0] = *(const bf16x8*)(LB + bRow[n + 2] + cx0);
        BH[n][1] = *(const bf16x8*)(LB + bRow[n + 2] + cx1);
    }
    asm volatile("s_waitcnt lgkmcnt(4)" ::: "memory");
    __builtin_amdgcn_sched_barrier(0);
    __builtin_amdgcn_s_setprio(1);
    #pragma unroll
    for (int m = 0; m < 4; ++m)
        #pragma unroll
        for (int n = 0; n < 2; ++n) {
            acc[m][n] = __builtin_amdgcn_mfma_f32_16x16x32_bf16(AX[m][0], BL[n][0], acc[m][n], 0, 0, 0);
            acc[m][n] = __builtin_amdgcn_mfma_f32_16x16x32_bf16(AX[m][1], BL[n][1], acc[m][n], 0, 0, 0);
        }
    __builtin_amdgcn_s_setprio(0);
    __builtin_amdgcn_s_barrier();

    for (int it = 0; it < nit; ++it) {
        int kA = 2 * it + 2; if (kA >= nt) kA = 0;
        int kB = 2 * it + 3; if (kB >= nt) kB = 0;
        #pragma unroll
        for (int db = 0; db < 2; ++db) {
            const int DBB = db * 65536;
            const char* Lb = LB + DBB;
            const char* Ln = LB + (DBB ^ 65536);
            const int kst = db ? kB : kA;
            const bool full = (db == 0) || (it < nit - 1);

            // ================= P_A =================
            stgB(DBB, kst);
            __builtin_amdgcn_s_setprio(1);
            #pragma unroll
            for (int m = 0; m < 4; ++m) {                     // q2: A0 x BH
                #pragma unroll
                for (int n = 0; n < 2; ++n) {
                    acc[m][n + 2] = __builtin_amdgcn_mfma_f32_16x16x32_bf16(AX[m][0], BH[n][0], acc[m][n + 2], 0, 0, 0);
                    acc[m][n + 2] = __builtin_amdgcn_mfma_f32_16x16x32_bf16(AX[m][1], BH[n][1], acc[m][n + 2], 0, 0, 0);
                }
                // AX[m] (A0) dead -> refill with A1(t); drains under q2
                AX[m][0] = *(const bf16x8*)(Lb + aRow[m + 4] + cx0);
                AX[m][1] = *(const bf16x8*)(Lb + aRow[m + 4] + cx1);
            }
            __builtin_amdgcn_s_setprio(0);
            asm volatile("s_waitcnt lgkmcnt(0)" ::: "memory");
            __builtin_amdgcn_sched_barrier(0);
            __builtin_amdgcn_s_setprio(1);
            #pragma unroll
            for (int m = 0; m < 4; ++m)                       // q3: A1 x BH
                #pragma unroll
                for (int n = 0; n < 2; ++n) {
                    acc[m + 4][n + 2] = __builtin_amdgcn_mfma_f32_16x16x32_bf16(AX[m][0], BH[n][0], acc[m + 4][n + 2], 0, 0, 0);
                    acc[m + 4][n + 2] = __builtin_amdgcn_mfma_f32_16x16x32_bf16(AX[m][1], BH[n][1], acc[m + 4][n + 2], 0, 0, 0);
                }
            __builtin_amdgcn_s_setprio(0);
            asm volatile("s_waitcnt vmcnt(4)" ::: "memory");  // t+1 landed (FIFO)
            __builtin_amdgcn_s_barrier();
            __builtin_amdgcn_sched_barrier(0);

            // ================= P_B =================
            __builtin_amdgcn_s_setprio(1);
            #pragma unroll
            for (int m = 0; m < 4; ++m) {                     // q4: A1 x BL
                #pragma unroll
                for (int n = 0; n < 2; ++n) {
                    acc[m + 4][n] = __builtin_amdgcn_mfma_f32_16x16x32_bf16(AX[m][0], BL[n][0], acc[m + 4][n], 0, 0, 0);
                    acc[m + 4][n] = __builtin_amdgcn_mfma_f32_16x16x32_bf16(AX[m][1], BL[n][1], acc[m + 4][n], 0, 0, 0);
                }
                if (full) {
                    // AX[m] (A1) dead -> refill with A0(t+1) from other dbuf
                    AX[m][0] = *(const bf16x8*)(Ln + aRow[m] + cx0);
                    AX[m][1] = *(const bf16x8*)(Ln + aRow[m] + cx1);
                }
            }
            __builtin_amdgcn_s_setprio(0);
            __builtin_amdgcn_sched_barrier(0);
            stgA(DBB, kst);
            if (full) {
                #pragma unroll
                for (int n = 0; n < 2; ++n) {                  // BL <- B0(t+1)
                    BL[n][0] = *(const bf16x8*)(Ln + bRow[n]     + cx0);
                    BL[n][1] = *(const bf16x8*)(Ln + bRow[n]     + cx1);
                }
                #pragma unroll
                for (int n = 0; n < 2; ++n) {                  // BH <- B1(t+1), last
                    BH[n][0] = *(const bf16x8*)(Ln + bRow[n + 2] + cx0);
                    BH[n][1] = *(const bf16x8*)(Ln + bRow[n + 2] + cx1);
                }
                asm volatile("s_waitcnt lgkmcnt(4)" ::: "memory");  // AX+BL done; BH under q1
                __builtin_amdgcn_sched_barrier(0);
                __builtin_amdgcn_s_setprio(1);
                #pragma unroll
                for (int m = 0; m < 4; ++m)                   // q1(t+1): A0 x B0
                    #pragma unroll
                    for (int n = 0; n < 2; ++n) {
                        acc[m][n] = __builtin_amdgcn_mfma_f32_16x16x32_bf16(AX[m][0], BL[n][0], acc[m][n], 0, 0, 0);
                        acc[m][n] = __builtin_amdgcn_mfma_f32_16x16x32_bf16(AX[m][1], BL[n][1], acc[m][n], 0, 0, 0);
                    }
                __builtin_amdgcn_s_setprio(0);
            }
            __builtin_amdgcn_s_barrier();
        }
    }

    asm volatile("s_waitcnt vmcnt(0)" ::: "memory");
    __builtin_amdgcn_s_barrier();

    // epilogue: per-wave private 16KB LDS region, chunk-XOR swizzle
    const int lg = l >> 4;
    const long wrow = rowBase + hm * 128;
    const long wcol = colBase + q * 64;
    char* ep = LB + w * 16384;

    if (EPI == 2) {
        #pragma unroll
        for (int mh = 0; mh < 2; ++mh) {
            #pragma unroll
            for (int m = 0; m < 4; ++m) {
                #pragma unroll
                for (int n = 0; n < 4; ++n) {
                    f32x4 v = acc[mh * 4 + m][n];
                    #pragma unroll
                    for (int r = 0; r < 4; ++r) {
                        int rowr = m * 16 + lg * 4 + r;
                        int chnk = (n * 4 + (lr >> 2)) ^ (rowr & 7);
                        *(float*)(ep + rowr * 256 + chnk * 16 + (lr & 3) * 4) = v[r];
                    }
                }
            }
            asm volatile("s_waitcnt lgkmcnt(0)" ::: "memory");
            #pragma unroll
            for (int i = 0; i < 16; ++i) {
                int rr = i * 4 + (l >> 4);
                float4 lv = *(float4*)(ep + rr * 256 + (((l & 15) ^ (rr & 7)) * 16));
                long off = (wrow + mh * 64 + rr) * N + wcol + (l & 15) * 4;
                float4 rv = *(const float4*)(res + off);
                lv.x += rv.x; lv.y += rv.y; lv.z += rv.z; lv.w += rv.w;
                *(float4*)((float*)C + off) = lv;
            }
            if (mh == 0) { asm volatile("s_waitcnt lgkmcnt(0) vmcnt(0)" ::: "memory"); }
        }
    } else {
        #pragma unroll
        for (int m = 0; m < 8; ++m) {
            #pragma unroll
            for (int n = 0; n < 4; ++n) {
                f32x4 v = acc[m][n];
                #pragma unroll
                for (int r = 0; r < 4; ++r) {
                    int rowr = m * 16 + lg * 4 + r;
                    int chnk = (n * 2 + (lr >> 3)) ^ (rowr & 7);
                    float val = (EPI == 1) ? fmaxf(v[r], 0.f) : v[r];
                    *(bf16*)(ep + rowr * 128 + chnk * 16 + (lr & 7) * 2) = (bf16)val;
                }
            }
        }
        asm volatile("s_waitcnt lgkmcnt(0)" ::: "memory");
        #pragma unroll
        for (int i = 0; i < 16; ++i) {
            int rr = i * 8 + (l >> 3);
            uint4 lv = *(uint4*)(ep + rr * 128 + (((l & 7) ^ (rr & 7)) * 16));
            *(uint4*)((bf16*)C + (wrow + rr) * N + wcol + (l & 7) * 8) = lv;
        }
    }
}

extern "C" void kernel_launch(void* const* d_in, const int* in_sizes, int n_in,
                              void* d_out, int out_size, void* d_ws, size_t ws_size,
                              hipStream_t stream) {
    const float* x      = (const float*)d_in[0];
    const float* W_in   = (const float*)d_in[1];
    const float* cw     = (const float*)d_in[2];
    const float* cb     = (const float*)d_in[3];
    const float* W_out  = (const float*)d_in[4];
    const float* W_mlp1 = (const float*)d_in[5];
    const float* W_mlp2 = (const float*)d_in[6];
    float* out = (float*)d_out;

    char* ws  = (char*)d_ws;
    bf16* wW  = (bf16*)(ws);                    // 33.55 MB (max bf16 weight)
    bf16* h   = (bf16*)(ws + 33554432);         // 33.55 MB (h / h2)
    bf16* xz  = (bf16*)(ws + 67108864);         // 134.2 MB (xz / m1)
    float* x2 = (float*)(ws + 201326592);       // 67.1 MB
    bf16* y   = xz + D_INNER;                   // in-place over z half, lda = 8192
    bf16* m1  = xz;

    dim3 blk(256);
    dim3 gblk(512);

    // mamba branch
    prep_kernel<<<dim3(ROWS + 8192), blk, 0, stream>>>(x, h, W_in, wW, 16777216/8);
    gemm_bt<0><<<dim3(1024), gblk, 0, stream>>>(h, D_MODEL, wW, xz, nullptr, 2*D_INNER, D_MODEL, 32);
    convf2b_kernel<<<dim3(16384 + 4096), blk, 0, stream>>>(xz, cw, cb, W_out, wW, 8388608/8);
    gemm_bt<2><<<dim3(256), gblk, 0, stream>>>(y, 2*D_INNER, wW, x2, x, D_MODEL, D_INNER, 8);

    // mlp branch
    prep_kernel<<<dim3(ROWS + 8192), blk, 0, stream>>>(x2, h, W_mlp1, wW, 16777216/8);
    gemm_bt<1><<<dim3(1024), gblk, 0, stream>>>(h, D_MODEL, wW, m1, nullptr, 4*D_MODEL, D_MODEL, 32);
    f2b_kernel<<<dim3(8192), blk, 0, stream>>>(W_mlp2, wW, 16777216/8);
    gemm_bt<2><<<dim3(256), gblk, 0, stream>>>(m1, 4*D_MODEL, wW, out, x2, D_MODEL, 4*D_MODEL, 8);
}

// Round 13
// 932.046 us; speedup vs baseline: 3.8635x; 1.0288x over previous
//
#include <hip/hip_runtime.h>
#include <hip/hip_bf16.h>

typedef __bf16 bf16;
typedef __bf16 bf16x8 __attribute__((ext_vector_type(8)));
typedef __bf16 bf16x4 __attribute__((ext_vector_type(4)));
typedef float f32x4 __attribute__((ext_vector_type(4)));

#define D_MODEL 2048
#define D_INNER 4096
#define ROWS    8192   // B*T

__device__ __forceinline__ void gload_lds16(const void* g, void* l) {
    __builtin_amdgcn_global_load_lds(
        (const __attribute__((address_space(1))) void*)g,
        (__attribute__((address_space(3))) void*)l, 16, 0, 0);
}

// ---------------- device bodies ----------------
__device__ __forceinline__ void f2b_body(const float* __restrict__ in,
                                         bf16* __restrict__ out, int i, int n8) {
    if (i >= n8) return;
    long base = (long)i * 8;
    float4 a = *(const float4*)(in + base);
    float4 b = *(const float4*)(in + base + 4);
    bf16x8 o;
    o[0] = (bf16)a.x; o[1] = (bf16)a.y; o[2] = (bf16)a.z; o[3] = (bf16)a.w;
    o[4] = (bf16)b.x; o[5] = (bf16)b.y; o[6] = (bf16)b.z; o[7] = (bf16)b.w;
    *(bf16x8*)(out + base) = o;
}

__device__ __forceinline__ void rmsnorm_body(const float* __restrict__ x,
                                             bf16* __restrict__ h, int row) {
    const float* xr = x + (long)row * D_MODEL;
    float4 v0 = ((const float4*)xr)[threadIdx.x * 2];
    float4 v1 = ((const float4*)xr)[threadIdx.x * 2 + 1];
    float ss = v0.x*v0.x + v0.y*v0.y + v0.z*v0.z + v0.w*v0.w
             + v1.x*v1.x + v1.y*v1.y + v1.z*v1.z + v1.w*v1.w;
    #pragma unroll
    for (int o = 32; o; o >>= 1) ss += __shfl_xor(ss, o, 64);
    __shared__ float red[4];
    if ((threadIdx.x & 63) == 0) red[threadIdx.x >> 6] = ss;
    __syncthreads();
    float tot = red[0] + red[1] + red[2] + red[3];
    float scale = 45.254834f / fmaxf(sqrtf(tot), 1e-12f);
    bf16x8 o;
    o[0] = (bf16)(v0.x*scale); o[1] = (bf16)(v0.y*scale);
    o[2] = (bf16)(v0.z*scale); o[3] = (bf16)(v0.w*scale);
    o[4] = (bf16)(v1.x*scale); o[5] = (bf16)(v1.y*scale);
    o[6] = (bf16)(v1.z*scale); o[7] = (bf16)(v1.w*scale);
    *(bf16x8*)(h + (long)row * D_MODEL + threadIdx.x * 8) = o;
}

// bf16-input rmsnorm (for x2 stored as bf16)
__device__ __forceinline__ void rmsnorm_body_b16(const bf16* __restrict__ x,
                                                 bf16* __restrict__ h, int row) {
    const bf16* xr = x + (long)row * D_MODEL;
    bf16x8 v = *(const bf16x8*)(xr + threadIdx.x * 8);
    float f[8];
    float ss = 0.f;
    #pragma unroll
    for (int e = 0; e < 8; ++e) { f[e] = (float)v[e]; ss += f[e] * f[e]; }
    #pragma unroll
    for (int o = 32; o; o >>= 1) ss += __shfl_xor(ss, o, 64);
    __shared__ float red[4];
    if ((threadIdx.x & 63) == 0) red[threadIdx.x >> 6] = ss;
    __syncthreads();
    float tot = red[0] + red[1] + red[2] + red[3];
    float scale = 45.254834f / fmaxf(sqrtf(tot), 1e-12f);
    bf16x8 o;
    #pragma unroll
    for (int e = 0; e < 8; ++e) o[e] = (bf16)(f[e] * scale);
    *(bf16x8*)(h + (long)row * D_MODEL + threadIdx.x * 8) = o;
}

__device__ __forceinline__ void conv_body(bf16* __restrict__ xz,
                                          const float* __restrict__ cw,
                                          const float* __restrict__ cb, int idx) {
    const int c8  = idx & 511;
    const int row = idx >> 9;
    const int t   = row & 2047;
    const int c0  = c8 * 8;
    float acc[8];
    float wv[8][4];
    #pragma unroll
    for (int e = 0; e < 8; ++e) {
        float4 f = ((const float4*)cw)[c0 + e];
        wv[e][0] = f.x; wv[e][1] = f.y; wv[e][2] = f.z; wv[e][3] = f.w;
        acc[e] = cb[c0 + e];
    }
    #pragma unroll
    for (int j = 0; j < 4; ++j) {
        if (t + j - 3 >= 0) {
            bf16x8 xv = *(const bf16x8*)(xz + (long)(row + j - 3) * (2*D_INNER) + c0);
            #pragma unroll
            for (int e = 0; e < 8; ++e) acc[e] += (float)xv[e] * wv[e][j];
        }
    }
    bf16* zp = xz + (long)row * (2*D_INNER) + D_INNER + c0;
    bf16x8 zv = *(const bf16x8*)zp;
    bf16x8 yv;
    #pragma unroll
    for (int e = 0; e < 8; ++e) {
        float xc = acc[e];
        float s1 = xc / (1.f + __expf(-xc));
        float z  = (float)zv[e];
        float s2 = z / (1.f + __expf(-z));
        yv[e] = (bf16)(s1 * s2);
    }
    *(bf16x8*)zp = yv;
}

// ---------------- merged elementwise kernels ----------------
__global__ __launch_bounds__(256) void prep_kernel(const float* __restrict__ x,
                                                   bf16* __restrict__ h,
                                                   const float* __restrict__ w,
                                                   bf16* __restrict__ wOut, int n8) {
    if ((int)blockIdx.x < ROWS) rmsnorm_body(x, h, blockIdx.x);
    else f2b_body(w, wOut, (blockIdx.x - ROWS) * 256 + threadIdx.x, n8);
}

// rmsnorm_b16 (8192) + f2b W_mlp1 (8192) + f2b W_mlp2 (8192)
__global__ __launch_bounds__(256) void prep2_kernel(const bf16* __restrict__ x2b,
                                                    bf16* __restrict__ h,
                                                    const float* __restrict__ w1,
                                                    bf16* __restrict__ w1o,
                                                    const float* __restrict__ w2,
                                                    bf16* __restrict__ w2o, int n8) {
    if ((int)blockIdx.x < ROWS) rmsnorm_body_b16(x2b, h, blockIdx.x);
    else if ((int)blockIdx.x < 2 * ROWS)
        f2b_body(w1, w1o, (blockIdx.x - ROWS) * 256 + threadIdx.x, n8);
    else
        f2b_body(w2, w2o, (blockIdx.x - 2 * ROWS) * 256 + threadIdx.x, n8);
}

__global__ __launch_bounds__(256) void convf2b_kernel(bf16* __restrict__ xz,
                                                      const float* __restrict__ cw,
                                                      const float* __restrict__ cb,
                                                      const float* __restrict__ w,
                                                      bf16* __restrict__ wOut, int n8) {
    if ((int)blockIdx.x < 16384) conv_body(xz, cw, cb, blockIdx.x * 256 + threadIdx.x);
    else f2b_body(w, wOut, (blockIdx.x - 16384) * 256 + threadIdx.x, n8);
}

// ---------------- bf16 GEMM v11: C = A @ B^T (+ epilogue) ------------------
// v10 core; micro changes: stage clusters split 2+2 (B halves around q2,
// A halves around the BL reads in P_B), BH refills moved inside q4.
// FIFO per tile: B0,B1,A0,A1 -> vmcnt(4) at P_A end retires tile t+1 exactly.
// EPI: 0 = bf16, 1 = relu+bf16, 2 = fp32-res add -> bf16 out,
//      3 = bf16-res add -> fp32 out
template<int EPI>
__global__ __launch_bounds__(512, 2) void gemm_bt(
        const bf16* __restrict__ A, long lda,
        const bf16* __restrict__ B,
        void* __restrict__ C, const void* __restrict__ res,
        int N, int K, int gx) {
    __shared__ __align__(16) char LB[131072];
    const int tid = threadIdx.x;
    const int w   = tid >> 6;
    const int l   = tid & 63;
    const int lr  = l & 15;

    int bx, by;
    if (gx == 32) {
        const int xcd = blockIdx.x & 7, i = blockIdx.x >> 3;
        by = (xcd >> 1) * 8 + (i >> 4);
        bx = (xcd & 1) * 16 + (i & 15);
    } else {
        const int qq = gridDim.x >> 3;
        const int sw = (blockIdx.x & 7) * qq + (blockIdx.x >> 3);
        bx = sw % gx; by = sw / gx;
    }
    const long rowBase = (long)by * 256;
    const long colBase = (long)bx * 256;

    const int srow = w * 8 + (l >> 3);
    const int schk = (l & 7) ^ ((l >> 3) & 7);
    const bf16* aSrc = A + (rowBase + srow) * lda + schk * 8;
    const bf16* bSrc = B + (colBase + srow) * (long)K + schk * 8;
    const long lda64 = 64 * lda;
    const long ldb64 = 64 * (long)K;
    const int  w1024 = w * 1024;

    auto stgA0 = [&](int DBB, int kt) {
        const bf16* s = aSrc + (long)kt * 64;
        gload_lds16(s,            LB + DBB +     0 + w1024);
        gload_lds16(s +   lda64,  LB + DBB +  8192 + w1024);
    };
    auto stgA1 = [&](int DBB, int kt) {
        const bf16* s = aSrc + (long)kt * 64;
        gload_lds16(s + 2*lda64,  LB + DBB + 16384 + w1024);
        gload_lds16(s + 3*lda64,  LB + DBB + 24576 + w1024);
    };
    auto stgB0 = [&](int DBB, int kt) {
        const bf16* s = bSrc + (long)kt * 64;
        gload_lds16(s,            LB + DBB + 32768 + w1024);
        gload_lds16(s +   ldb64,  LB + DBB + 40960 + w1024);
    };
    auto stgB1 = [&](int DBB, int kt) {
        const bf16* s = bSrc + (long)kt * 64;
        gload_lds16(s + 2*ldb64,  LB + DBB + 49152 + w1024);
        gload_lds16(s + 3*ldb64,  LB + DBB + 57344 + w1024);
    };

    const int cx0 = (((l >> 4)    ) ^ (l & 7)) << 4;
    const int cx1 = (((l >> 4) + 4) ^ (l & 7)) << 4;
    const int hm = w >> 2;
    const int q  = w & 3;
    int aRow[8], bRow[4];
    #pragma unroll
    for (int m = 0; m < 8; ++m) aRow[m] = hm * 16384 + (m * 16 + lr) * 128;
    #pragma unroll
    for (int n = 0; n < 4; ++n)
        bRow[n] = 32768 + (q >> 1) * 16384 + ((q & 1) * 64 + n * 16 + lr) * 128;

    const int nt  = K >> 6;
    const int nit = nt >> 1;
    f32x4 acc[8][4] = {};
    bf16x8 AX[4][2], BL[2][2], BH[2][2];

    stgB0(0, 0); stgB1(0, 0); stgA0(0, 0); stgA1(0, 0);
    stgB0(65536, 1); stgB1(65536, 1); stgA0(65536, 1); stgA1(65536, 1);
    asm volatile("s_waitcnt vmcnt(8)" ::: "memory");
    __builtin_amdgcn_s_barrier();
    __builtin_amdgcn_sched_barrier(0);
    #pragma unroll
    for (int m = 0; m < 4; ++m) {
        AX[m][0] = *(const bf16x8*)(LB + aRow[m] + cx0);
        AX[m][1] = *(const bf16x8*)(LB + aRow[m] + cx1);
    }
    #pragma unroll
    for (int n = 0; n < 2; ++n) {
        BL[n][0] = *(const bf16x8*)(LB + bRow[n]     + cx0);
        BL[n][1] = *(const bf16x8*)(LB + bRow[n]     + cx1);
    }
    #pragma unroll
    for (int n = 0; n < 2; ++n) {
        BH[n][0] = *(const bf16x8*)(LB + bRow[n + 2] + cx0);
        BH[n][1] = *(const bf16x8*)(LB + bRow[n + 2] + cx1);
    }
    asm volatile("s_waitcnt lgkmcnt(4)" ::: "memory");
    __builtin_amdgcn_sched_barrier(0);
    __builtin_amdgcn_s_setprio(1);
    #pragma unroll
    for (int m = 0; m < 4; ++m)
        #pragma unroll
        for (int n = 0; n < 2; ++n) {
            acc[m][n] = __builtin_amdgcn_mfma_f32_16x16x32_bf16(AX[m][0], BL[n][0], acc[m][n], 0, 0, 0);
            acc[m][n] = __builtin_amdgcn_mfma_f32_16x16x32_bf16(AX[m][1], BL[n][1], acc[m][n], 0, 0, 0);
        }
    __builtin_amdgcn_s_setprio(0);
    __builtin_amdgcn_s_barrier();

    for (int it = 0; it < nit; ++it) {
        int kA = 2 * it + 2; if (kA >= nt) kA = 0;
        int kB = 2 * it + 3; if (kB >= nt) kB = 0;
        #pragma unroll
        for (int db = 0; db < 2; ++db) {
            const int DBB = db * 65536;
            const char* Lb = LB + DBB;
            const char* Ln = LB + (DBB ^ 65536);
            const int kst = db ? kB : kA;
            const bool full = (db == 0) || (it < nit - 1);

            // ================= P_A =================
            stgB0(DBB, kst);
            __builtin_amdgcn_s_setprio(1);
            #pragma unroll
            for (int m = 0; m < 4; ++m) {                     // q2: A0 x BH
                #pragma unroll
                for (int n = 0; n < 2; ++n) {
                    acc[m][n + 2] = __builtin_amdgcn_mfma_f32_16x16x32_bf16(AX[m][0], BH[n][0], acc[m][n + 2], 0, 0, 0);
                    acc[m][n + 2] = __builtin_amdgcn_mfma_f32_16x16x32_bf16(AX[m][1], BH[n][1], acc[m][n + 2], 0, 0, 0);
                }
                AX[m][0] = *(const bf16x8*)(Lb + aRow[m + 4] + cx0);
                AX[m][1] = *(const bf16x8*)(Lb + aRow[m + 4] + cx1);
            }
            __builtin_amdgcn_s_setprio(0);
            stgB1(DBB, kst);
            asm volatile("s_waitcnt lgkmcnt(0)" ::: "memory");
            __builtin_amdgcn_sched_barrier(0);
            __builtin_amdgcn_s_setprio(1);
            #pragma unroll
            for (int m = 0; m < 4; ++m)                       // q3: A1 x BH
                #pragma unroll
                for (int n = 0; n < 2; ++n) {
                    acc[m + 4][n + 2] = __builtin_amdgcn_mfma_f32_16x16x32_bf16(AX[m][0], BH[n][0], acc[m + 4][n + 2], 0, 0, 0);
                    acc[m + 4][n + 2] = __builtin_amdgcn_mfma_f32_16x16x32_bf16(AX[m][1], BH[n][1], acc[m + 4][n + 2], 0, 0, 0);
                }
            __builtin_amdgcn_s_setprio(0);
            asm volatile("s_waitcnt vmcnt(4)" ::: "memory");  // t+1 landed (FIFO)
            __builtin_amdgcn_s_barrier();
            __builtin_amdgcn_sched_barrier(0);

            // ================= P_B =================
            __builtin_amdgcn_s_setprio(1);
            #pragma unroll
            for (int m = 0; m < 4; ++m) {                     // q4: A1 x BL
                #pragma unroll
                for (int n = 0; n < 2; ++n) {
                    acc[m + 4][n] = __builtin_amdgcn_mfma_f32_16x16x32_bf16(AX[m][0], BL[n][0], acc[m + 4][n], 0, 0, 0);
                    acc[m + 4][n] = __builtin_amdgcn_mfma_f32_16x16x32_bf16(AX[m][1], BL[n][1], acc[m + 4][n], 0, 0, 0);
                }
                if (full) {
                    AX[m][0] = *(const bf16x8*)(Ln + aRow[m] + cx0);
                    AX[m][1] = *(const bf16x8*)(Ln + aRow[m] + cx1);
                    if (m < 2) {                               // BH refill under q4
                        BH[m][0] = *(const bf16x8*)(Ln + bRow[m + 2] + cx0);
                        BH[m][1] = *(const bf16x8*)(Ln + bRow[m + 2] + cx1);
                    }
                }
            }
            __builtin_amdgcn_s_setprio(0);
            __builtin_amdgcn_sched_barrier(0);
            stgA0(DBB, kst);
            if (full) {
                #pragma unroll
                for (int n = 0; n < 2; ++n) {                  // BL <- B0(t+1)
                    BL[n][0] = *(const bf16x8*)(Ln + bRow[n]     + cx0);
                    BL[n][1] = *(const bf16x8*)(Ln + bRow[n]     + cx1);
                }
            }
            stgA1(DBB, kst);
            if (full) {
                asm volatile("s_waitcnt lgkmcnt(0)" ::: "memory");
                __builtin_amdgcn_sched_barrier(0);
                __builtin_amdgcn_s_setprio(1);
                #pragma unroll
                for (int m = 0; m < 4; ++m)                   // q1(t+1): A0 x B0
                    #pragma unroll
                    for (int n = 0; n < 2; ++n) {
                        acc[m][n] = __builtin_amdgcn_mfma_f32_16x16x32_bf16(AX[m][0], BL[n][0], acc[m][n], 0, 0, 0);
                        acc[m][n] = __builtin_amdgcn_mfma_f32_16x16x32_bf16(AX[m][1], BL[n][1], acc[m][n], 0, 0, 0);
                    }
                __builtin_amdgcn_s_setprio(0);
            }
            __builtin_amdgcn_s_barrier();
        }
    }

    asm volatile("s_waitcnt vmcnt(0)" ::: "memory");
    __builtin_amdgcn_s_barrier();

    // epilogue
    const int lg = l >> 4;
    const long wrow = rowBase + hm * 128;
    const long wcol = colBase + q * 64;
    char* ep = LB + w * 16384;

    if (EPI == 3) {
        // bf16 res add -> fp32 out, two 64-row passes via fp32 LDS
        const bf16* rb = (const bf16*)res;
        #pragma unroll
        for (int mh = 0; mh < 2; ++mh) {
            #pragma unroll
            for (int m = 0; m < 4; ++m) {
                #pragma unroll
                for (int n = 0; n < 4; ++n) {
                    f32x4 v = acc[mh * 4 + m][n];
                    #pragma unroll
                    for (int r = 0; r < 4; ++r) {
                        int rowr = m * 16 + lg * 4 + r;
                        int chnk = (n * 4 + (lr >> 2)) ^ (rowr & 7);
                        *(float*)(ep + rowr * 256 + chnk * 16 + (lr & 3) * 4) = v[r];
                    }
                }
            }
            asm volatile("s_waitcnt lgkmcnt(0)" ::: "memory");
            #pragma unroll
            for (int i = 0; i < 16; ++i) {
                int rr = i * 4 + (l >> 4);
                float4 lv = *(float4*)(ep + rr * 256 + (((l & 15) ^ (rr & 7)) * 16));
                long off = (wrow + mh * 64 + rr) * N + wcol + (l & 15) * 4;
                bf16x4 rv = *(const bf16x4*)(rb + off);
                lv.x += (float)rv[0]; lv.y += (float)rv[1];
                lv.z += (float)rv[2]; lv.w += (float)rv[3];
                *(float4*)((float*)C + off) = lv;
            }
            if (mh == 0) { asm volatile("s_waitcnt lgkmcnt(0) vmcnt(0)" ::: "memory"); }
        }
    } else {
        // bf16 out (EPI 0/1/2), single pass [128][64] bf16 LDS
        const float* rf = (const float*)res;
        #pragma unroll
        for (int m = 0; m < 8; ++m) {
            #pragma unroll
            for (int n = 0; n < 4; ++n) {
                f32x4 v = acc[m][n];
                #pragma unroll
                for (int r = 0; r < 4; ++r) {
                    int rowr = m * 16 + lg * 4 + r;
                    int chnk = (n * 2 + (lr >> 3)) ^ (rowr & 7);
                    float val = v[r];
                    if (EPI == 1) val = fmaxf(val, 0.f);
                    if (EPI == 2) val += rf[(wrow + rowr) * N + wcol + n * 16 + lr];
                    *(bf16*)(ep + rowr * 128 + chnk * 16 + (lr & 7) * 2) = (bf16)val;
                }
            }
        }
        asm volatile("s_waitcnt lgkmcnt(0)" ::: "memory");
        #pragma unroll
        for (int i = 0; i < 16; ++i) {
            int rr = i * 8 + (l >> 3);
            uint4 lv = *(uint4*)(ep + rr * 128 + (((l & 7) ^ (rr & 7)) * 16));
            *(uint4*)((bf16*)C + (wrow + rr) * N + wcol + (l & 7) * 8) = lv;
        }
    }
}

extern "C" void kernel_launch(void* const* d_in, const int* in_sizes, int n_in,
                              void* d_out, int out_size, void* d_ws, size_t ws_size,
                              hipStream_t stream) {
    const float* x      = (const float*)d_in[0];
    const float* W_in   = (const float*)d_in[1];
    const float* cw     = (const float*)d_in[2];
    const float* cb     = (const float*)d_in[3];
    const float* W_out  = (const float*)d_in[4];
    const float* W_mlp1 = (const float*)d_in[5];
    const float* W_mlp2 = (const float*)d_in[6];
    float* out = (float*)d_out;

    char* ws  = (char*)d_ws;
    bf16* wW  = (bf16*)(ws);                    // 33.55 MB
    bf16* h   = (bf16*)(ws + 33554432);         // 33.55 MB
    bf16* xz  = (bf16*)(ws + 67108864);         // 134.2 MB (xz / m1)
    bf16* x2b = (bf16*)(ws + 201326592);        // 33.55 MB (bf16 residual)
    bf16* wW2 = (bf16*)(ws + 234881024);        // 33.55 MB (W_mlp2 bf16)
    bf16* y   = xz + D_INNER;                   // z-half in place, lda = 8192
    bf16* m1  = xz;

    dim3 blk(256);
    dim3 gblk(512);

    // mamba branch
    prep_kernel<<<dim3(ROWS + 8192), blk, 0, stream>>>(x, h, W_in, wW, 16777216/8);
    gemm_bt<0><<<dim3(1024), gblk, 0, stream>>>(h, D_MODEL, wW, xz, nullptr, 2*D_INNER, D_MODEL, 32);
    convf2b_kernel<<<dim3(16384 + 4096), blk, 0, stream>>>(xz, cw, cb, W_out, wW, 8388608/8);
    gemm_bt<2><<<dim3(256), gblk, 0, stream>>>(y, 2*D_INNER, wW, x2b, x, D_MODEL, D_INNER, 8);

    // mlp branch
    prep2_kernel<<<dim3(3 * ROWS), blk, 0, stream>>>(x2b, h, W_mlp1, wW, W_mlp2, wW2, 16777216/8);
    gemm_bt<1><<<dim3(1024), gblk, 0, stream>>>(h, D_MODEL, wW, m1, nullptr, 4*D_MODEL, D_MODEL, 32);
    gemm_bt<3><<<dim3(256), gblk, 0, stream>>>(m1, 4*D_MODEL, wW2, out, x2b, D_MODEL, 4*D_MODEL, 8);
}